// Round 1
// baseline (1244.332 us; speedup 1.0000x reference)
//
#include <hip/hip_runtime.h>
#include <stdint.h>

#define C_DIM 2048
#define H_NUM 16
#define DH    128
#define S_LEN 1024
#define T_LEN 256
#define B_SZ  4
#define L_ROWS 4096   // B*S
#define LY_ROWS 1024  // B*T
#define F_DIM 8192

typedef __attribute__((ext_vector_type(4))) float f32x4;
typedef __attribute__((ext_vector_type(8))) __bf16 bf16x8;
typedef __attribute__((ext_vector_type(4))) unsigned short us4;
typedef __attribute__((ext_vector_type(8))) unsigned short us8;
typedef unsigned short u16;

__device__ __forceinline__ u16 f2bf(float f) {
  union { float f; uint32_t u; } v; v.f = f;
  uint32_t r = v.u + 0x7FFFu + ((v.u >> 16) & 1u);
  return (u16)(r >> 16);
}
__device__ __forceinline__ float bf2f(u16 h) {
  union { uint32_t u; float f; } v; v.u = ((uint32_t)h) << 16;
  return v.f;
}

typedef __attribute__((address_space(1))) void gvoid;
typedef __attribute__((address_space(3))) void lvoid;
__device__ __forceinline__ void gl_lds16(const void* g, void* l) {
  __builtin_amdgcn_global_load_lds((gvoid*)g, (lvoid*)l, 16, 0, 0);
}

// ---------------- fp32 -> bf16 conversion ----------------
__global__ void k_cvt(const float* __restrict__ src, u16* __restrict__ dst, int n) {
  int i = (blockIdx.x * blockDim.x + threadIdx.x) * 4;
  int stride = gridDim.x * blockDim.x * 4;
  for (; i < n; i += stride) {
    float4 v = *(const float4*)(src + i);
    us4 o;
    o[0] = f2bf(v.x); o[1] = f2bf(v.y); o[2] = f2bf(v.z); o[3] = f2bf(v.w);
    *(us4*)(dst + i) = o;
  }
}

// ---------------- LN + adaLN modulation ----------------
__global__ __launch_bounds__(256)
void k_modln(const float* __restrict__ x, const float* __restrict__ t,
             const float* __restrict__ tab, u16* __restrict__ out,
             int scale_idx, int shift_idx) {
  int row = blockIdx.x;
  int tid = threadIdx.x;
  const float* xr = x + (size_t)row * C_DIM;
  int c0 = tid * 8;
  float4 a = *(const float4*)(xr + c0);
  float4 b = *(const float4*)(xr + c0 + 4);
  float v[8] = {a.x, a.y, a.z, a.w, b.x, b.y, b.z, b.w};
  float s = 0.f, ss = 0.f;
#pragma unroll
  for (int j = 0; j < 8; ++j) { s += v[j]; ss += v[j] * v[j]; }
#pragma unroll
  for (int m = 1; m < 64; m <<= 1) { s += __shfl_xor(s, m); ss += __shfl_xor(ss, m); }
  __shared__ float red[8];
  int wid = tid >> 6;
  if ((tid & 63) == 0) { red[wid * 2] = s; red[wid * 2 + 1] = ss; }
  __syncthreads();
  s  = red[0] + red[2] + red[4] + red[6];
  ss = red[1] + red[3] + red[5] + red[7];
  float mean = s * (1.f / C_DIM);
  float var  = ss * (1.f / C_DIM) - mean * mean;
  float rstd = rsqrtf(var + 1e-6f);
  const float* trow = t + (size_t)row * (6 * C_DIM);
  const float* tsc = trow + scale_idx * C_DIM + c0;
  const float* tsh = trow + shift_idx * C_DIM + c0;
  const float* gsc = tab + scale_idx * C_DIM + c0;
  const float* gsh = tab + shift_idx * C_DIM + c0;
  us8 o;
#pragma unroll
  for (int j = 0; j < 8; ++j) {
    float scv = 1.f + gsc[j] + tsc[j];
    float shv = gsh[j] + tsh[j];
    o[j] = f2bf((v[j] - mean) * rstd * scv + shv);
  }
  *(us8*)(out + (size_t)row * C_DIM + c0) = o;
}

// ---------------- GEMM: out = A[M,K] @ W[N,K]^T (+epilogue) ----------------
// EPI 0: bf16(acc+bias) -> outB
// EPI 1: bf16(gelu(acc+bias)) -> outB
// EPI 2: o = resid + (gate_tab[col]+gate_t[row*6C+col])*(acc+bias); outF=o; outB?=bf16(o)
// EPI 3: o = resid + (acc+bias); outF=o
template<int EPI>
__global__ __launch_bounds__(256)
void k_gemm(const u16* __restrict__ A, const u16* __restrict__ W,
            const float* __restrict__ bias,
            float* __restrict__ outF, u16* __restrict__ outB,
            const float* __restrict__ resid,
            const float* __restrict__ gate_t, const float* __restrict__ gate_tab,
            int M, int N, int K) {
  __shared__ __align__(16) u16 lA[128 * 32];
  __shared__ __align__(16) u16 lB[128 * 32];
  int tid = threadIdx.x;
  int m0 = blockIdx.y * 128, n0 = blockIdx.x * 128;
  int wid = tid >> 6, lane = tid & 63;
  int wr = (wid >> 1) * 64, wc = (wid & 1) * 64;
  int lr = lane & 15, lg = lane >> 4;
  f32x4 zero4 = {0.f, 0.f, 0.f, 0.f};
  f32x4 acc[4][4];
#pragma unroll
  for (int m = 0; m < 4; ++m)
#pragma unroll
    for (int n = 0; n < 4; ++n) acc[m][n] = zero4;

  for (int k0 = 0; k0 < K; k0 += 32) {
#pragma unroll
    for (int i = 0; i < 2; ++i) {
      int flat = i * 4096 + tid * 16;
      int row = flat >> 6, colb = flat & 63;
      gl_lds16((const char*)A + ((size_t)(m0 + row) * K + k0) * 2 + colb, (char*)lA + flat);
      gl_lds16((const char*)W + ((size_t)(n0 + row) * K + k0) * 2 + colb, (char*)lB + flat);
    }
    __syncthreads();
    bf16x8 af[4], bfr[4];
    int ko = lg * 16;
#pragma unroll
    for (int m = 0; m < 4; ++m)
      af[m] = *(const bf16x8*)((const char*)lA + (wr + m * 16 + lr) * 64 + ko);
#pragma unroll
    for (int n = 0; n < 4; ++n)
      bfr[n] = *(const bf16x8*)((const char*)lB + (wc + n * 16 + lr) * 64 + ko);
#pragma unroll
    for (int m = 0; m < 4; ++m)
#pragma unroll
      for (int n = 0; n < 4; ++n)
        acc[m][n] = __builtin_amdgcn_mfma_f32_16x16x32_bf16(af[m], bfr[n], acc[m][n], 0, 0, 0);
    __syncthreads();
  }

#pragma unroll
  for (int m = 0; m < 4; ++m) {
    int row0 = m0 + wr + m * 16 + lg * 4;
#pragma unroll
    for (int n = 0; n < 4; ++n) {
      int col = n0 + wc + n * 16 + lr;
      float bv = bias[col];
#pragma unroll
      for (int r = 0; r < 4; ++r) {
        int row = row0 + r;
        size_t idx = (size_t)row * N + col;
        float val = acc[m][n][r] + bv;
        if constexpr (EPI == 0) {
          outB[idx] = f2bf(val);
        } else if constexpr (EPI == 1) {
          float x3 = val * val * val;
          float g = 0.5f * val * (1.f + tanhf(0.7978845608f * (val + 0.044715f * x3)));
          outB[idx] = f2bf(g);
        } else if constexpr (EPI == 2) {
          float g = gate_tab[col] + gate_t[(size_t)row * (6 * C_DIM) + col];
          float o = resid[idx] + g * val;
          outF[idx] = o;
          if (outB) outB[idx] = f2bf(o);
        } else {
          outF[idx] = resid[idx] + val;
        }
      }
    }
  }
}

// ---------------- RoPE on q and k (in place, bf16) ----------------
__global__ void k_rope(u16* __restrict__ q, u16* __restrict__ k,
                       const float* __restrict__ freqs) {
  int idx = blockIdx.x * blockDim.x + threadIdx.x;
  int total = L_ROWS * C_DIM / 8;
  for (; idx < total; idx += gridDim.x * blockDim.x) {
    int e = idx * 8;
    int row = e >> 11;          // /C_DIM
    int col = e & (C_DIM - 1);
    int s = row & (S_LEN - 1);
    int i0 = (col & (DH - 1)) >> 1;
    float4 fr = *(const float4*)(freqs + s * (DH / 2) + i0);
    float cs[4], sn[4];
    float fv[4] = {fr.x, fr.y, fr.z, fr.w};
#pragma unroll
    for (int j = 0; j < 4; ++j) sincosf(fv[j], &sn[j], &cs[j]);
    us8 qa = *(us8*)(q + e);
    us8 ka = *(us8*)(k + e);
#pragma unroll
    for (int p = 0; p < 4; ++p) {
      float a = bf2f(qa[2 * p]), b = bf2f(qa[2 * p + 1]);
      qa[2 * p]     = f2bf(a * cs[p] - b * sn[p]);
      qa[2 * p + 1] = f2bf(a * sn[p] + b * cs[p]);
      float a2 = bf2f(ka[2 * p]), b2 = bf2f(ka[2 * p + 1]);
      ka[2 * p]     = f2bf(a2 * cs[p] - b2 * sn[p]);
      ka[2 * p + 1] = f2bf(a2 * sn[p] + b2 * cs[p]);
    }
    *(us8*)(q + e) = qa;
    *(us8*)(k + e) = ka;
  }
}

// ---------------- V transpose: [b*Lkv+kv][h*DH+d] -> [bh][d][kv] ----------------
__global__ void k_transpose_v(const u16* __restrict__ v, u16* __restrict__ vt, int Lkv) {
  __shared__ u16 tile[32][33];
  int bh = blockIdx.x, b = bh >> 4, h = bh & 15;
  int k0 = blockIdx.y * 32, d0 = blockIdx.z * 32;
  int tx = threadIdx.x, ty = threadIdx.y;
  const u16* src = v + (size_t)(b * Lkv) * C_DIM + h * DH;
#pragma unroll
  for (int j = 0; j < 32; j += 8)
    tile[ty + j][tx] = src[(size_t)(k0 + ty + j) * C_DIM + d0 + tx];
  __syncthreads();
  u16* dst = vt + (size_t)bh * DH * Lkv;
#pragma unroll
  for (int j = 0; j < 32; j += 8)
    dst[(size_t)(d0 + ty + j) * Lkv + k0 + tx] = tile[tx][ty + j];
}

// ---------------- flash attention ----------------
// Q,K: [b*Lq + s][h*DH + d] bf16; Vt: [bh][d][kv] bf16; O like Q.
__global__ __launch_bounds__(256)
void k_flash(const u16* __restrict__ Q, const u16* __restrict__ K,
             const u16* __restrict__ Vt, u16* __restrict__ O,
             int Lq, int Lkv, float scale) {
  __shared__ __align__(16) u16 lK[64 * 128];      // [key][d], src-XOR swizzled
  __shared__ __align__(16) u16 lV[128 * 64];      // [d][key], src-XOR swizzled
  __shared__ __align__(16) u16 lP[4][16 * 72];    // per-wave P, 144B rows
  int bh = blockIdx.x, b = bh >> 4, h = bh & 15;
  int tid = threadIdx.x, wid = tid >> 6, lane = tid & 63;
  int lr = lane & 15, lg = lane >> 4;
  int q0 = blockIdx.y * 64 + wid * 16;
  const u16* Qb = Q + ((size_t)(b * Lq) + q0) * C_DIM + h * DH;
  const u16* Kb = K + (size_t)(b * Lkv) * C_DIM + h * DH;
  const u16* Vb = Vt + (size_t)bh * DH * Lkv;

  bf16x8 qf[4];
#pragma unroll
  for (int ks = 0; ks < 4; ++ks)
    qf[ks] = *(const bf16x8*)(Qb + (size_t)lr * C_DIM + ks * 32 + lg * 8);

  f32x4 zero4 = {0.f, 0.f, 0.f, 0.f};
  f32x4 o[8];
#pragma unroll
  for (int n = 0; n < 8; ++n) o[n] = zero4;
  float mrow[4] = {-3.0e38f, -3.0e38f, -3.0e38f, -3.0e38f};
  float lrow[4] = {0.f, 0.f, 0.f, 0.f};

  int nsteps = Lkv >> 6;
  for (int kt = 0; kt < nsteps; ++kt) {
#pragma unroll
    for (int i = 0; i < 4; ++i) {
      int flat = i * 4096 + tid * 16;
      int key = flat >> 8, inner = flat & 255;
      int ksrc = inner ^ ((key & 7) << 4);
      gl_lds16((const char*)Kb + ((size_t)(kt * 64 + key) * C_DIM) * 2 + ksrc, (char*)lK + flat);
      int d = flat >> 7, keyb = flat & 127;
      int vsrc = keyb ^ ((d & 7) << 4);
      gl_lds16((const char*)Vb + ((size_t)d * Lkv) * 2 + kt * 128 + vsrc, (char*)lV + flat);
    }
    __syncthreads();

    f32x4 sc[4];
#pragma unroll
    for (int c = 0; c < 4; ++c) sc[c] = zero4;
#pragma unroll
    for (int c = 0; c < 4; ++c) {
      int key = c * 16 + lr;
#pragma unroll
      for (int ks = 0; ks < 4; ++ks) {
        int off = (ks * 64 + lg * 16) ^ ((key & 7) << 4);
        bf16x8 kf = *(const bf16x8*)((const char*)lK + key * 256 + off);
        sc[c] = __builtin_amdgcn_mfma_f32_16x16x32_bf16(qf[ks], kf, sc[c], 0, 0, 0);
      }
    }
    // online softmax (row = 4*lg + r, 16 key-lanes per row)
#pragma unroll
    for (int r = 0; r < 4; ++r) {
      float s0 = sc[0][r] * scale, s1 = sc[1][r] * scale;
      float s2 = sc[2][r] * scale, s3 = sc[3][r] * scale;
      float mx = fmaxf(fmaxf(s0, s1), fmaxf(s2, s3));
#pragma unroll
      for (int m = 1; m < 16; m <<= 1) mx = fmaxf(mx, __shfl_xor(mx, m));
      float mnew = fmaxf(mrow[r], mx);
      float alpha = exp2f((mrow[r] - mnew) * 1.44269504f);
      mrow[r] = mnew;
      float p0 = exp2f((s0 - mnew) * 1.44269504f);
      float p1 = exp2f((s1 - mnew) * 1.44269504f);
      float p2 = exp2f((s2 - mnew) * 1.44269504f);
      float p3 = exp2f((s3 - mnew) * 1.44269504f);
      float psum = p0 + p1 + p2 + p3;
#pragma unroll
      for (int m = 1; m < 16; m <<= 1) psum += __shfl_xor(psum, m);
      lrow[r] = lrow[r] * alpha + psum;
#pragma unroll
      for (int n = 0; n < 8; ++n) o[n][r] *= alpha;
      u16* pr = lP[wid] + (4 * lg + r) * 72;
      pr[lr]      = f2bf(p0);
      pr[16 + lr] = f2bf(p1);
      pr[32 + lr] = f2bf(p2);
      pr[48 + lr] = f2bf(p3);
    }
    asm volatile("s_waitcnt lgkmcnt(0)" ::: "memory");
    __builtin_amdgcn_sched_barrier(0);
    // PV
#pragma unroll
    for (int half = 0; half < 2; ++half) {
      bf16x8 pf = *(const bf16x8*)(lP[wid] + lr * 72 + half * 32 + lg * 8);
#pragma unroll
      for (int n = 0; n < 8; ++n) {
        int d = n * 16 + lr;
        int off = (half * 64 + lg * 16) ^ ((d & 7) << 4);
        bf16x8 vf = *(const bf16x8*)((const char*)lV + d * 128 + off);
        o[n] = __builtin_amdgcn_mfma_f32_16x16x32_bf16(pf, vf, o[n], 0, 0, 0);
      }
    }
    __syncthreads();
  }

  u16* Ob = O + ((size_t)(b * Lq) + q0) * C_DIM + h * DH;
#pragma unroll
  for (int n = 0; n < 8; ++n) {
    int d = n * 16 + lr;
#pragma unroll
    for (int r = 0; r < 4; ++r) {
      int qr = 4 * lg + r;
      Ob[(size_t)qr * C_DIM + d] = f2bf(o[n][r] / lrow[r]);
    }
  }
}

// ---------------- host ----------------
extern "C" void kernel_launch(void* const* d_in, const int* in_sizes, int n_in,
                              void* d_out, int out_size, void* d_ws, size_t ws_size,
                              hipStream_t stream) {
  const float* x     = (const float*)d_in[0];
  const float* y     = (const float*)d_in[1];
  const float* t     = (const float*)d_in[2];
  const float* freqs = (const float*)d_in[3];
  const float* tab   = (const float*)d_in[4];
  const float* Wq_s = (const float*)d_in[5];
  const float* bq_s = (const float*)d_in[6];
  const float* Wk_s = (const float*)d_in[7];
  const float* bk_s = (const float*)d_in[8];
  const float* Wv_s = (const float*)d_in[9];
  const float* bv_s = (const float*)d_in[10];
  const float* Wo_s = (const float*)d_in[11];
  const float* bo_s = (const float*)d_in[12];
  const float* Wq_c = (const float*)d_in[13];
  const float* bq_c = (const float*)d_in[14];
  const float* Wk_c = (const float*)d_in[15];
  const float* bk_c = (const float*)d_in[16];
  const float* Wv_c = (const float*)d_in[17];
  const float* bv_c = (const float*)d_in[18];
  const float* Wo_c = (const float*)d_in[19];
  const float* bo_c = (const float*)d_in[20];
  const float* W_fc1 = (const float*)d_in[21];
  const float* b_fc1 = (const float*)d_in[22];
  const float* W_fc2 = (const float*)d_in[23];
  const float* b_fc2 = (const float*)d_in[24];

  // workspace layout (bytes)
  const size_t SZ_CC  = (size_t)C_DIM * C_DIM * 2;   // 8,388,608
  const size_t SZ_FC  = (size_t)F_DIM * C_DIM * 2;   // 33,554,432
  const size_t SZ_LC  = (size_t)L_ROWS * C_DIM * 2;  // 16,777,216
  const size_t SZ_YC  = (size_t)LY_ROWS * C_DIM * 2; //  4,194,304
  char* ws = (char*)d_ws;
  size_t off = 0;
  u16* wq_s = (u16*)(ws + off); off += SZ_CC;
  u16* wk_s = (u16*)(ws + off); off += SZ_CC;
  u16* wv_s = (u16*)(ws + off); off += SZ_CC;
  u16* wo_s = (u16*)(ws + off); off += SZ_CC;
  u16* wq_c = (u16*)(ws + off); off += SZ_CC;
  u16* wk_c = (u16*)(ws + off); off += SZ_CC;
  u16* wv_c = (u16*)(ws + off); off += SZ_CC;
  u16* wo_c = (u16*)(ws + off); off += SZ_CC;
  u16* wfc1 = (u16*)(ws + off); off += SZ_FC;
  u16* wfc2 = (u16*)(ws + off); off += SZ_FC;
  u16* ybf  = (u16*)(ws + off); off += SZ_YC;
  u16* xm   = (u16*)(ws + off); off += SZ_LC;
  u16* qb   = (u16*)(ws + off); off += SZ_LC;  // h overlays qb..ao (67,108,864 B)
  u16* kb   = (u16*)(ws + off); off += SZ_LC;
  u16* vb   = (u16*)(ws + off); off += SZ_LC;
  u16* ao   = (u16*)(ws + off); off += SZ_LC;
  u16* hbuf = qb;                               // [L, F] bf16
  float* x1 = (float*)(ws + off); off += (size_t)L_ROWS * C_DIM * 4;
  u16* x1bf = (u16*)(ws + off); off += SZ_LC;
  u16* kc   = (u16*)(ws + off); off += SZ_YC;
  u16* vc   = (u16*)(ws + off); off += SZ_YC;
  u16* vt   = (u16*)(ws + off); off += SZ_LC;  // self V^T [bh][128][1024]
  u16* vtc  = (u16*)(ws + off); off += SZ_YC;  // cross V^T [bh][128][256]
  if (ws_size < off) return;  // insufficient scratch -> visible failure

  auto cvt = [&](const float* s, u16* d, int n) {
    int blocks = (n / 4 + 255) / 256; if (blocks > 4096) blocks = 4096;
    k_cvt<<<blocks, 256, 0, stream>>>(s, d, n);
  };
  cvt(Wq_s, wq_s, C_DIM * C_DIM);
  cvt(Wk_s, wk_s, C_DIM * C_DIM);
  cvt(Wv_s, wv_s, C_DIM * C_DIM);
  cvt(Wo_s, wo_s, C_DIM * C_DIM);
  cvt(Wq_c, wq_c, C_DIM * C_DIM);
  cvt(Wk_c, wk_c, C_DIM * C_DIM);
  cvt(Wv_c, wv_c, C_DIM * C_DIM);
  cvt(Wo_c, wo_c, C_DIM * C_DIM);
  cvt(W_fc1, wfc1, F_DIM * C_DIM);
  cvt(W_fc2, wfc2, F_DIM * C_DIM);
  cvt(y, ybf, LY_ROWS * C_DIM);

  const float ascale = 0.08838834764831845f;  // 1/sqrt(128)

  // xm = LN(x)*(1+scale_msa)+shift_msa
  k_modln<<<L_ROWS, 256, 0, stream>>>(x, t, tab, xm, 1, 0);
  // self qkv
  k_gemm<0><<<dim3(C_DIM / 128, L_ROWS / 128), 256, 0, stream>>>(
      xm, wq_s, bq_s, nullptr, qb, nullptr, nullptr, nullptr, L_ROWS, C_DIM, C_DIM);
  k_gemm<0><<<dim3(C_DIM / 128, L_ROWS / 128), 256, 0, stream>>>(
      xm, wk_s, bk_s, nullptr, kb, nullptr, nullptr, nullptr, L_ROWS, C_DIM, C_DIM);
  k_gemm<0><<<dim3(C_DIM / 128, L_ROWS / 128), 256, 0, stream>>>(
      xm, wv_s, bv_s, nullptr, vb, nullptr, nullptr, nullptr, L_ROWS, C_DIM, C_DIM);
  k_rope<<<2048, 256, 0, stream>>>(qb, kb, freqs);
  k_transpose_v<<<dim3(B_SZ * H_NUM, S_LEN / 32, DH / 32), dim3(32, 8), 0, stream>>>(vb, vt, S_LEN);
  k_flash<<<dim3(B_SZ * H_NUM, S_LEN / 64), 256, 0, stream>>>(qb, kb, vt, ao, S_LEN, S_LEN, ascale);
  // x1 = x + gate_msa*(ao@Wo_s^T+bo_s); also bf16 copy
  k_gemm<2><<<dim3(C_DIM / 128, L_ROWS / 128), 256, 0, stream>>>(
      ao, wo_s, bo_s, x1, x1bf, x, t + 2 * C_DIM, tab + 2 * C_DIM, L_ROWS, C_DIM, C_DIM);
  // cross
  k_gemm<0><<<dim3(C_DIM / 128, L_ROWS / 128), 256, 0, stream>>>(
      x1bf, wq_c, bq_c, nullptr, qb, nullptr, nullptr, nullptr, L_ROWS, C_DIM, C_DIM);
  k_gemm<0><<<dim3(C_DIM / 128, LY_ROWS / 128), 256, 0, stream>>>(
      ybf, wk_c, bk_c, nullptr, kc, nullptr, nullptr, nullptr, LY_ROWS, C_DIM, C_DIM);
  k_gemm<0><<<dim3(C_DIM / 128, LY_ROWS / 128), 256, 0, stream>>>(
      ybf, wv_c, bv_c, nullptr, vc, nullptr, nullptr, nullptr, LY_ROWS, C_DIM, C_DIM);
  k_transpose_v<<<dim3(B_SZ * H_NUM, T_LEN / 32, DH / 32), dim3(32, 8), 0, stream>>>(vc, vtc, T_LEN);
  k_flash<<<dim3(B_SZ * H_NUM, S_LEN / 64), 256, 0, stream>>>(qb, kc, vtc, ao, S_LEN, T_LEN, ascale);
  // x1 += ao@Wo_c^T + bo_c (in place)
  k_gemm<3><<<dim3(C_DIM / 128, L_ROWS / 128), 256, 0, stream>>>(
      ao, wo_c, bo_c, x1, nullptr, x1, nullptr, nullptr, L_ROWS, C_DIM, C_DIM);
  // MLP
  k_modln<<<L_ROWS, 256, 0, stream>>>(x1, t, tab, xm, 4, 3);
  k_gemm<1><<<dim3(F_DIM / 128, L_ROWS / 128), 256, 0, stream>>>(
      xm, wfc1, b_fc1, nullptr, hbuf, nullptr, nullptr, nullptr, L_ROWS, F_DIM, C_DIM);
  k_gemm<2><<<dim3(C_DIM / 128, L_ROWS / 128), 256, 0, stream>>>(
      hbuf, wfc2, b_fc2, (float*)d_out, nullptr, x1, t + 5 * C_DIM, tab + 5 * C_DIM,
      L_ROWS, C_DIM, F_DIM);
}

// Round 2
// 1025.669 us; speedup vs baseline: 1.2132x; 1.2132x over previous
//
#include <hip/hip_runtime.h>
#include <stdint.h>

#define C_DIM 2048
#define H_NUM 16
#define DH    128
#define S_LEN 1024
#define T_LEN 256
#define B_SZ  4
#define L_ROWS 4096   // B*S
#define LY_ROWS 1024  // B*T
#define F_DIM 8192

typedef __attribute__((ext_vector_type(4))) float f32x4;
typedef __attribute__((ext_vector_type(8))) __bf16 bf16x8;
typedef __attribute__((ext_vector_type(4))) unsigned short us4;
typedef __attribute__((ext_vector_type(8))) unsigned short us8;
typedef unsigned short u16;

__device__ __forceinline__ u16 f2bf(float f) {
  union { float f; uint32_t u; } v; v.f = f;
  uint32_t r = v.u + 0x7FFFu + ((v.u >> 16) & 1u);
  return (u16)(r >> 16);
}
__device__ __forceinline__ float bf2f(u16 h) {
  union { uint32_t u; float f; } v; v.u = ((uint32_t)h) << 16;
  return v.f;
}

typedef __attribute__((address_space(1))) void gvoid;
typedef __attribute__((address_space(3))) void lvoid;
__device__ __forceinline__ void gl_lds16(const void* g, void* l) {
  __builtin_amdgcn_global_load_lds((gvoid*)g, (lvoid*)l, 16, 0, 0);
}

template<int N> __device__ __forceinline__ void wait_vmcnt() {
  if constexpr (N == 0) asm volatile("s_waitcnt vmcnt(0)" ::: "memory");
  else if constexpr (N == 3) asm volatile("s_waitcnt vmcnt(3)" ::: "memory");
  else if constexpr (N == 4) asm volatile("s_waitcnt vmcnt(4)" ::: "memory");
}
__device__ __forceinline__ void barrier_raw() {
  asm volatile("s_barrier" ::: "memory");
}

// ---------------- fp32 -> bf16 conversion ----------------
__global__ void k_cvt(const float* __restrict__ src, u16* __restrict__ dst, int n) {
  int i = (blockIdx.x * blockDim.x + threadIdx.x) * 4;
  int stride = gridDim.x * blockDim.x * 4;
  for (; i < n; i += stride) {
    float4 v = *(const float4*)(src + i);
    us4 o;
    o[0] = f2bf(v.x); o[1] = f2bf(v.y); o[2] = f2bf(v.z); o[3] = f2bf(v.w);
    *(us4*)(dst + i) = o;
  }
}

// ---------------- LN + adaLN modulation ----------------
__global__ __launch_bounds__(256)
void k_modln(const float* __restrict__ x, const float* __restrict__ t,
             const float* __restrict__ tab, u16* __restrict__ out,
             int scale_idx, int shift_idx) {
  int row = blockIdx.x;
  int tid = threadIdx.x;
  const float* xr = x + (size_t)row * C_DIM;
  int c0 = tid * 8;
  float4 a = *(const float4*)(xr + c0);
  float4 b = *(const float4*)(xr + c0 + 4);
  float v[8] = {a.x, a.y, a.z, a.w, b.x, b.y, b.z, b.w};
  float s = 0.f, ss = 0.f;
#pragma unroll
  for (int j = 0; j < 8; ++j) { s += v[j]; ss += v[j] * v[j]; }
#pragma unroll
  for (int m = 1; m < 64; m <<= 1) { s += __shfl_xor(s, m); ss += __shfl_xor(ss, m); }
  __shared__ float red[8];
  int wid = tid >> 6;
  if ((tid & 63) == 0) { red[wid * 2] = s; red[wid * 2 + 1] = ss; }
  __syncthreads();
  s  = red[0] + red[2] + red[4] + red[6];
  ss = red[1] + red[3] + red[5] + red[7];
  float mean = s * (1.f / C_DIM);
  float var  = ss * (1.f / C_DIM) - mean * mean;
  float rstd = rsqrtf(var + 1e-6f);
  const float* trow = t + (size_t)row * (6 * C_DIM);
  const float* tsc = trow + scale_idx * C_DIM + c0;
  const float* tsh = trow + shift_idx * C_DIM + c0;
  const float* gsc = tab + scale_idx * C_DIM + c0;
  const float* gsh = tab + shift_idx * C_DIM + c0;
  us8 o;
#pragma unroll
  for (int j = 0; j < 8; ++j) {
    float scv = 1.f + gsc[j] + tsc[j];
    float shv = gsh[j] + tsh[j];
    o[j] = f2bf((v[j] - mean) * rstd * scv + shv);
  }
  *(us8*)(out + (size_t)row * C_DIM + c0) = o;
}

// ---------------- GEMM v2: 256xBN tile, BK=32, 3-stage pipeline ----------------
// out = A[M,K] @ W[N,K]^T (+epilogue). 512 threads = 8 waves (2M x 4N).
// Per-wave output: 128 x (BN/4). LDS triple-buffered, XOR-swizzled slots.
// EPI 0: bf16(acc+bias) -> o{0,1,2} split by col>>sec_shift, ld=out_ld
// EPI 1: bf16(gelu(acc+bias)) -> o0
// EPI 2: o = resid + gate*(acc+bias); outF=o; o0?=bf16(o)
// EPI 3: o = resid + (acc+bias); outF=o
template<int BN, int EPI>
__global__ __launch_bounds__(512, 2)
void k_gemm2(const u16* __restrict__ A, const u16* __restrict__ W,
             const float* __restrict__ bias0, const float* __restrict__ bias1,
             const float* __restrict__ bias2,
             u16* __restrict__ o0, u16* __restrict__ o1, u16* __restrict__ o2,
             int sec_shift, int out_ld,
             float* __restrict__ outF, const float* __restrict__ resid,
             const float* __restrict__ gate_t, const float* __restrict__ gate_tab,
             int M, int N, int K, int nbx) {
  constexpr int ASZ = 256 * 32;          // u16 elements per A tile (16 KB)
  constexpr int BSZ = BN * 32;           // u16 elements per B tile
  constexpr int TSZ = ASZ + BSZ;
  constexpr int NREP = BN / 64;          // 4 (BN=256) or 2 (BN=128)
  constexpr int WNT  = BN / 4;           // per-wave N span
  constexpr int BCALLS = BN / 128;       // 2 or 1
  constexpr int CALLS  = 2 + BCALLS;     // staging instrs per K-tile
  __shared__ __align__(16) u16 lds[3 * TSZ];

  int tid = threadIdx.x;
  // bijective XCD swizzle (grids here are multiples of 8, but keep general)
  int nwg = gridDim.x;
  int q8 = nwg >> 3, r8 = nwg & 7;
  int xcd = blockIdx.x & 7, local = blockIdx.x >> 3;
  int wgid = (xcd < r8 ? xcd * (q8 + 1) : r8 * (q8 + 1) + (xcd - r8) * q8) + local;
  int bx = wgid % nbx, by = wgid / nbx;
  int m0 = by * 256, n0 = bx * BN;

  int wid = tid >> 6, lane = tid & 63;
  int wm = wid >> 2, wn = wid & 3;
  int lr = lane & 15, lg = lane >> 4;
  // read-side swizzle: slot = lg ^ ((row^(row>>2))&3); row bases are mult of 16
  int slotr8 = ((lg ^ (lr & 3) ^ ((lr >> 2) & 3)) & 3) * 8;   // element offset
  // stage-side inverse swizzle (per-lane constant)
  int slotg8 = (((tid & 3) ^ ((tid >> 2) & 3) ^ ((tid >> 4) & 3)) & 3) * 8;
  int rstage = tid >> 2;                 // 0..127 row-within-call

  auto stageA = [&](int j, int kst, int so) {
    int row = j * 128 + rstage;
    gl_lds16((const char*)A + ((size_t)(m0 + row) * K + kst + slotg8) * 2,
             (char*)lds + (size_t)so * 2 + j * 8192 + tid * 16);
  };
  auto stageB = [&](int j, int kst, int so) {
    int row = j * 128 + rstage;
    gl_lds16((const char*)W + ((size_t)(n0 + row) * K + kst + slotg8) * 2,
             (char*)lds + (size_t)(so + ASZ) * 2 + j * 8192 + tid * 16);
  };

  f32x4 zero4 = {0.f, 0.f, 0.f, 0.f};
  f32x4 acc[8][NREP];
#pragma unroll
  for (int m = 0; m < 8; ++m)
#pragma unroll
    for (int n = 0; n < NREP; ++n) acc[m][n] = zero4;

  int NT = K >> 5;
  // prologue: stage tiles 0,1
  stageA(0, 0, 0); stageB(0, 0, 0); stageA(1, 0, 0);
  if constexpr (BCALLS == 2) stageB(1, 0, 0);
  stageA(0, 32, TSZ); stageB(0, 32, TSZ); stageA(1, 32, TSZ);
  if constexpr (BCALLS == 2) stageB(1, 32, TSZ);
  wait_vmcnt<CALLS>();
  barrier_raw();

  int c = 0;
  for (int t = 0; t < NT; ++t) {
    int c2 = c >= 1 ? c - 1 : 2;        // (c+2)%3
    int curo = c * TSZ, stgo = c2 * TSZ;
    int kst = (t + 2) << 5;
    bool st = (t + 2) < NT;
    const u16* curA = lds + curo;
    const u16* curB = lds + curo + ASZ;

    bf16x8 afr[4], bfr[NREP];
    // ---- phase 0 (mh=0) ----
#pragma unroll
    for (int n = 0; n < NREP; ++n)
      bfr[n] = *(const bf16x8*)(curB + (wn * WNT + n * 16 + lr) * 32 + slotr8);
#pragma unroll
    for (int m = 0; m < 4; ++m)
      afr[m] = *(const bf16x8*)(curA + (wm * 128 + m * 16 + lr) * 32 + slotr8);
    if (st) { stageA(0, kst, stgo); stageB(0, kst, stgo); }
    barrier_raw();
    __builtin_amdgcn_s_setprio(1);
#pragma unroll
    for (int m = 0; m < 4; ++m)
#pragma unroll
      for (int n = 0; n < NREP; ++n)
        acc[m][n] = __builtin_amdgcn_mfma_f32_16x16x32_bf16(afr[m], bfr[n], acc[m][n], 0, 0, 0);
    __builtin_amdgcn_s_setprio(0);
    barrier_raw();
    // ---- phase 1 (mh=1) ----
#pragma unroll
    for (int m = 0; m < 4; ++m)
      afr[m] = *(const bf16x8*)(curA + (wm * 128 + 64 + m * 16 + lr) * 32 + slotr8);
    if (st) { stageA(1, kst, stgo); if constexpr (BCALLS == 2) stageB(1, kst, stgo); }
    barrier_raw();
    __builtin_amdgcn_s_setprio(1);
#pragma unroll
    for (int m = 0; m < 4; ++m)
#pragma unroll
      for (int n = 0; n < NREP; ++n)
        acc[4 + m][n] = __builtin_amdgcn_mfma_f32_16x16x32_bf16(afr[m], bfr[n], acc[4 + m][n], 0, 0, 0);
    __builtin_amdgcn_s_setprio(0);
    if (t + 1 < NT) {
      if (st) wait_vmcnt<CALLS>(); else wait_vmcnt<0>();
      barrier_raw();
    }
    c = c == 2 ? 0 : c + 1;
  }

  // ---- epilogue ----
#pragma unroll
  for (int mf = 0; mf < 8; ++mf) {
    int row0 = m0 + wm * 128 + mf * 16 + lg * 4;
#pragma unroll
    for (int nf = 0; nf < NREP; ++nf) {
      int col = n0 + wn * WNT + nf * 16 + lr;
      if constexpr (EPI == 0) {
        int sec = col >> sec_shift;
        const float* bp = sec == 0 ? bias0 : (sec == 1 ? bias1 : bias2);
        u16* op = sec == 0 ? o0 : (sec == 1 ? o1 : o2);
        int cs = col & ((1 << sec_shift) - 1);
        float bv = bp[cs];
#pragma unroll
        for (int r = 0; r < 4; ++r)
          op[(size_t)(row0 + r) * out_ld + cs] = f2bf(acc[mf][nf][r] + bv);
      } else if constexpr (EPI == 1) {
        float bv = bias0[col];
#pragma unroll
        for (int r = 0; r < 4; ++r) {
          float val = acc[mf][nf][r] + bv;
          float x3 = val * val * val;
          float g = 0.5f * val * (1.f + tanhf(0.7978845608f * (val + 0.044715f * x3)));
          o0[(size_t)(row0 + r) * out_ld + col] = f2bf(g);
        }
      } else if constexpr (EPI == 2) {
        float bv = bias0[col];
        float gt = gate_tab[col];
#pragma unroll
        for (int r = 0; r < 4; ++r) {
          int row = row0 + r;
          size_t idx = (size_t)row * N + col;
          float g = gt + gate_t[(size_t)row * (6 * C_DIM) + col];
          float o = resid[idx] + g * (acc[mf][nf][r] + bv);
          outF[idx] = o;
          if (o0) o0[idx] = f2bf(o);
        }
      } else {
        float bv = bias0[col];
#pragma unroll
        for (int r = 0; r < 4; ++r) {
          size_t idx = (size_t)(row0 + r) * N + col;
          outF[idx] = resid[idx] + (acc[mf][nf][r] + bv);
        }
      }
    }
  }
}

// ---------------- RoPE on q and k (in place, bf16) ----------------
__global__ void k_rope(u16* __restrict__ q, u16* __restrict__ k,
                       const float* __restrict__ freqs) {
  int idx = blockIdx.x * blockDim.x + threadIdx.x;
  int total = L_ROWS * C_DIM / 8;
  for (; idx < total; idx += gridDim.x * blockDim.x) {
    int e = idx * 8;
    int row = e >> 11;
    int col = e & (C_DIM - 1);
    int s = row & (S_LEN - 1);
    int i0 = (col & (DH - 1)) >> 1;
    float4 fr = *(const float4*)(freqs + s * (DH / 2) + i0);
    float cs[4], sn[4];
    float fv[4] = {fr.x, fr.y, fr.z, fr.w};
#pragma unroll
    for (int j = 0; j < 4; ++j) sincosf(fv[j], &sn[j], &cs[j]);
    us8 qa = *(us8*)(q + e);
    us8 ka = *(us8*)(k + e);
#pragma unroll
    for (int p = 0; p < 4; ++p) {
      float a = bf2f(qa[2 * p]), b = bf2f(qa[2 * p + 1]);
      qa[2 * p]     = f2bf(a * cs[p] - b * sn[p]);
      qa[2 * p + 1] = f2bf(a * sn[p] + b * cs[p]);
      float a2 = bf2f(ka[2 * p]), b2 = bf2f(ka[2 * p + 1]);
      ka[2 * p]     = f2bf(a2 * cs[p] - b2 * sn[p]);
      ka[2 * p + 1] = f2bf(a2 * sn[p] + b2 * cs[p]);
    }
    *(us8*)(q + e) = qa;
    *(us8*)(k + e) = ka;
  }
}

// ---------------- V transpose: [b*Lkv+kv][h*DH+d] -> [bh][d][kv] ----------------
__global__ void k_transpose_v(const u16* __restrict__ v, u16* __restrict__ vt, int Lkv) {
  __shared__ u16 tile[32][33];
  int bh = blockIdx.x, b = bh >> 4, h = bh & 15;
  int k0 = blockIdx.y * 32, d0 = blockIdx.z * 32;
  int tx = threadIdx.x, ty = threadIdx.y;
  const u16* src = v + (size_t)(b * Lkv) * C_DIM + h * DH;
#pragma unroll
  for (int j = 0; j < 32; j += 8)
    tile[ty + j][tx] = src[(size_t)(k0 + ty + j) * C_DIM + d0 + tx];
  __syncthreads();
  u16* dst = vt + (size_t)bh * DH * Lkv;
#pragma unroll
  for (int j = 0; j < 32; j += 8)
    dst[(size_t)(d0 + ty + j) * Lkv + k0 + tx] = tile[tx][ty + j];
}

// ---------------- flash attention ----------------
__global__ __launch_bounds__(256)
void k_flash(const u16* __restrict__ Q, const u16* __restrict__ K,
             const u16* __restrict__ Vt, u16* __restrict__ O,
             int Lq, int Lkv, float scale) {
  __shared__ __align__(16) u16 lK[64 * 128];
  __shared__ __align__(16) u16 lV[128 * 64];
  __shared__ __align__(16) u16 lP[4][16 * 72];
  int bh = blockIdx.x, b = bh >> 4, h = bh & 15;
  int tid = threadIdx.x, wid = tid >> 6, lane = tid & 63;
  int lr = lane & 15, lg = lane >> 4;
  int q0 = blockIdx.y * 64 + wid * 16;
  const u16* Qb = Q + ((size_t)(b * Lq) + q0) * C_DIM + h * DH;
  const u16* Kb = K + (size_t)(b * Lkv) * C_DIM + h * DH;
  const u16* Vb = Vt + (size_t)bh * DH * Lkv;

  bf16x8 qf[4];
#pragma unroll
  for (int ks = 0; ks < 4; ++ks)
    qf[ks] = *(const bf16x8*)(Qb + (size_t)lr * C_DIM + ks * 32 + lg * 8);

  f32x4 zero4 = {0.f, 0.f, 0.f, 0.f};
  f32x4 o[8];
#pragma unroll
  for (int n = 0; n < 8; ++n) o[n] = zero4;
  float mrow[4] = {-3.0e38f, -3.0e38f, -3.0e38f, -3.0e38f};
  float lrow[4] = {0.f, 0.f, 0.f, 0.f};

  int nsteps = Lkv >> 6;
  for (int kt = 0; kt < nsteps; ++kt) {
#pragma unroll
    for (int i = 0; i < 4; ++i) {
      int flat = i * 4096 + tid * 16;
      int key = flat >> 8, inner = flat & 255;
      int ksrc = inner ^ ((key & 7) << 4);
      gl_lds16((const char*)Kb + ((size_t)(kt * 64 + key) * C_DIM) * 2 + ksrc, (char*)lK + flat);
      int d = flat >> 7, keyb = flat & 127;
      int vsrc = keyb ^ ((d & 7) << 4);
      gl_lds16((const char*)Vb + ((size_t)d * Lkv) * 2 + kt * 128 + vsrc, (char*)lV + flat);
    }
    __syncthreads();

    f32x4 sc[4];
#pragma unroll
    for (int c = 0; c < 4; ++c) sc[c] = zero4;
#pragma unroll
    for (int c = 0; c < 4; ++c) {
      int key = c * 16 + lr;
#pragma unroll
      for (int ks = 0; ks < 4; ++ks) {
        int off = (ks * 64 + lg * 16) ^ ((key & 7) << 4);
        bf16x8 kf = *(const bf16x8*)((const char*)lK + key * 256 + off);
        sc[c] = __builtin_amdgcn_mfma_f32_16x16x32_bf16(qf[ks], kf, sc[c], 0, 0, 0);
      }
    }
#pragma unroll
    for (int r = 0; r < 4; ++r) {
      float s0 = sc[0][r] * scale, s1 = sc[1][r] * scale;
      float s2 = sc[2][r] * scale, s3 = sc[3][r] * scale;
      float mx = fmaxf(fmaxf(s0, s1), fmaxf(s2, s3));
#pragma unroll
      for (int m = 1; m < 16; m <<= 1) mx = fmaxf(mx, __shfl_xor(mx, m));
      float mnew = fmaxf(mrow[r], mx);
      float alpha = exp2f((mrow[r] - mnew) * 1.44269504f);
      mrow[r] = mnew;
      float p0 = exp2f((s0 - mnew) * 1.44269504f);
      float p1 = exp2f((s1 - mnew) * 1.44269504f);
      float p2 = exp2f((s2 - mnew) * 1.44269504f);
      float p3 = exp2f((s3 - mnew) * 1.44269504f);
      float psum = p0 + p1 + p2 + p3;
#pragma unroll
      for (int m = 1; m < 16; m <<= 1) psum += __shfl_xor(psum, m);
      lrow[r] = lrow[r] * alpha + psum;
#pragma unroll
      for (int n = 0; n < 8; ++n) o[n][r] *= alpha;
      u16* pr = lP[wid] + (4 * lg + r) * 72;
      pr[lr]      = f2bf(p0);
      pr[16 + lr] = f2bf(p1);
      pr[32 + lr] = f2bf(p2);
      pr[48 + lr] = f2bf(p3);
    }
    asm volatile("s_waitcnt lgkmcnt(0)" ::: "memory");
    __builtin_amdgcn_sched_barrier(0);
#pragma unroll
    for (int half = 0; half < 2; ++half) {
      bf16x8 pf = *(const bf16x8*)(lP[wid] + lr * 72 + half * 32 + lg * 8);
#pragma unroll
      for (int n = 0; n < 8; ++n) {
        int d = n * 16 + lr;
        int off = (half * 64 + lg * 16) ^ ((d & 7) << 4);
        bf16x8 vf = *(const bf16x8*)((const char*)lV + d * 128 + off);
        o[n] = __builtin_amdgcn_mfma_f32_16x16x32_bf16(pf, vf, o[n], 0, 0, 0);
      }
    }
    __syncthreads();
  }

  u16* Ob = O + ((size_t)(b * Lq) + q0) * C_DIM + h * DH;
#pragma unroll
  for (int n = 0; n < 8; ++n) {
    int d = n * 16 + lr;
#pragma unroll
    for (int r = 0; r < 4; ++r) {
      int qr = 4 * lg + r;
      Ob[(size_t)qr * C_DIM + d] = f2bf(o[n][r] / lrow[r]);
    }
  }
}

// ---------------- host ----------------
extern "C" void kernel_launch(void* const* d_in, const int* in_sizes, int n_in,
                              void* d_out, int out_size, void* d_ws, size_t ws_size,
                              hipStream_t stream) {
  const float* x     = (const float*)d_in[0];
  const float* y     = (const float*)d_in[1];
  const float* t     = (const float*)d_in[2];
  const float* freqs = (const float*)d_in[3];
  const float* tab   = (const float*)d_in[4];
  const float* Wq_s = (const float*)d_in[5];
  const float* bq_s = (const float*)d_in[6];
  const float* Wk_s = (const float*)d_in[7];
  const float* bk_s = (const float*)d_in[8];
  const float* Wv_s = (const float*)d_in[9];
  const float* bv_s = (const float*)d_in[10];
  const float* Wo_s = (const float*)d_in[11];
  const float* bo_s = (const float*)d_in[12];
  const float* Wq_c = (const float*)d_in[13];
  const float* bq_c = (const float*)d_in[14];
  const float* Wk_c = (const float*)d_in[15];
  const float* bk_c = (const float*)d_in[16];
  const float* Wv_c = (const float*)d_in[17];
  const float* bv_c = (const float*)d_in[18];
  const float* Wo_c = (const float*)d_in[19];
  const float* bo_c = (const float*)d_in[20];
  const float* W_fc1 = (const float*)d_in[21];
  const float* b_fc1 = (const float*)d_in[22];
  const float* W_fc2 = (const float*)d_in[23];
  const float* b_fc2 = (const float*)d_in[24];

  const size_t SZ_CC  = (size_t)C_DIM * C_DIM * 2;
  const size_t SZ_FC  = (size_t)F_DIM * C_DIM * 2;
  const size_t SZ_LC  = (size_t)L_ROWS * C_DIM * 2;
  const size_t SZ_YC  = (size_t)LY_ROWS * C_DIM * 2;
  char* ws = (char*)d_ws;
  size_t off = 0;
  u16* wq_s = (u16*)(ws + off); off += SZ_CC;   // wq_s..wv_s contiguous = QKV concat
  u16* wk_s = (u16*)(ws + off); off += SZ_CC;
  u16* wv_s = (u16*)(ws + off); off += SZ_CC;
  u16* wo_s = (u16*)(ws + off); off += SZ_CC;
  u16* wq_c = (u16*)(ws + off); off += SZ_CC;
  u16* wk_c = (u16*)(ws + off); off += SZ_CC;   // wk_c,wv_c contiguous = KV concat
  u16* wv_c = (u16*)(ws + off); off += SZ_CC;
  u16* wo_c = (u16*)(ws + off); off += SZ_CC;
  u16* wfc1 = (u16*)(ws + off); off += SZ_FC;
  u16* wfc2 = (u16*)(ws + off); off += SZ_FC;
  u16* ybf  = (u16*)(ws + off); off += SZ_YC;
  u16* xm   = (u16*)(ws + off); off += SZ_LC;
  u16* qb   = (u16*)(ws + off); off += SZ_LC;
  u16* kb   = (u16*)(ws + off); off += SZ_LC;
  u16* vb   = (u16*)(ws + off); off += SZ_LC;
  u16* ao   = (u16*)(ws + off); off += SZ_LC;
  u16* hbuf = qb;                               // [L, F] bf16 overlay
  float* x1 = (float*)(ws + off); off += (size_t)L_ROWS * C_DIM * 4;
  u16* x1bf = (u16*)(ws + off); off += SZ_LC;
  u16* kc   = (u16*)(ws + off); off += SZ_YC;
  u16* vc   = (u16*)(ws + off); off += SZ_YC;
  u16* vt   = (u16*)(ws + off); off += SZ_LC;
  u16* vtc  = (u16*)(ws + off); off += SZ_YC;
  if (ws_size < off) return;

  auto cvt = [&](const float* s, u16* d, int n) {
    int blocks = (n / 4 + 255) / 256; if (blocks > 4096) blocks = 4096;
    k_cvt<<<blocks, 256, 0, stream>>>(s, d, n);
  };
  cvt(Wq_s, wq_s, C_DIM * C_DIM);
  cvt(Wk_s, wk_s, C_DIM * C_DIM);
  cvt(Wv_s, wv_s, C_DIM * C_DIM);
  cvt(Wo_s, wo_s, C_DIM * C_DIM);
  cvt(Wq_c, wq_c, C_DIM * C_DIM);
  cvt(Wk_c, wk_c, C_DIM * C_DIM);
  cvt(Wv_c, wv_c, C_DIM * C_DIM);
  cvt(Wo_c, wo_c, C_DIM * C_DIM);
  cvt(W_fc1, wfc1, F_DIM * C_DIM);
  cvt(W_fc2, wfc2, F_DIM * C_DIM);
  cvt(y, ybf, LY_ROWS * C_DIM);

  const float ascale = 0.08838834764831845f;

  k_modln<<<L_ROWS, 256, 0, stream>>>(x, t, tab, xm, 1, 0);
  // fused self QKV: N = 6144, weights = [wq_s;wk_s;wv_s]
  k_gemm2<256, 0><<<24 * 16, 512, 0, stream>>>(
      xm, wq_s, bq_s, bk_s, bv_s, qb, kb, vb, 11, C_DIM,
      nullptr, nullptr, nullptr, nullptr, L_ROWS, 6144, C_DIM, 24);
  k_rope<<<2048, 256, 0, stream>>>(qb, kb, freqs);
  k_transpose_v<<<dim3(B_SZ * H_NUM, S_LEN / 32, DH / 32), dim3(32, 8), 0, stream>>>(vb, vt, S_LEN);
  k_flash<<<dim3(B_SZ * H_NUM, S_LEN / 64), 256, 0, stream>>>(qb, kb, vt, ao, S_LEN, S_LEN, ascale);
  // x1 = x + gate_msa*(ao@Wo_s^T+bo_s); bf16 mirror x1bf
  k_gemm2<128, 2><<<16 * 16, 512, 0, stream>>>(
      ao, wo_s, bo_s, nullptr, nullptr, x1bf, nullptr, nullptr, 30, C_DIM,
      x1, x, t + 2 * C_DIM, tab + 2 * C_DIM, L_ROWS, C_DIM, C_DIM, 16);
  // cross q
  k_gemm2<128, 0><<<16 * 16, 512, 0, stream>>>(
      x1bf, wq_c, bq_c, nullptr, nullptr, qb, nullptr, nullptr, 30, C_DIM,
      nullptr, nullptr, nullptr, nullptr, L_ROWS, C_DIM, C_DIM, 16);
  // fused cross KV: N = 4096, weights = [wk_c;wv_c]
  k_gemm2<128, 0><<<32 * 4, 512, 0, stream>>>(
      ybf, wk_c, bk_c, bv_c, bv_c, kc, vc, vc, 11, C_DIM,
      nullptr, nullptr, nullptr, nullptr, LY_ROWS, 4096, C_DIM, 32);
  k_transpose_v<<<dim3(B_SZ * H_NUM, T_LEN / 32, DH / 32), dim3(32, 8), 0, stream>>>(vc, vtc, T_LEN);
  k_flash<<<dim3(B_SZ * H_NUM, S_LEN / 64), 256, 0, stream>>>(qb, kc, vtc, ao, S_LEN, T_LEN, ascale);
  // x1 += ao@Wo_c^T + bo_c
  k_gemm2<128, 3><<<16 * 16, 512, 0, stream>>>(
      ao, wo_c, bo_c, nullptr, nullptr, nullptr, nullptr, nullptr, 30, C_DIM,
      x1, x1, nullptr, nullptr, L_ROWS, C_DIM, C_DIM, 16);
  // MLP
  k_modln<<<L_ROWS, 256, 0, stream>>>(x1, t, tab, xm, 4, 3);
  k_gemm2<256, 1><<<32 * 16, 512, 0, stream>>>(
      xm, wfc1, b_fc1, nullptr, nullptr, hbuf, nullptr, nullptr, 30, F_DIM,
      nullptr, nullptr, nullptr, nullptr, L_ROWS, F_DIM, C_DIM, 32);
  k_gemm2<128, 2><<<16 * 16, 512, 0, stream>>>(
      hbuf, wfc2, b_fc2, nullptr, nullptr, nullptr, nullptr, nullptr, 30, C_DIM,
      (float*)d_out, x1, t + 5 * C_DIM, tab + 5 * C_DIM, L_ROWS, C_DIM, F_DIM, 16);
}

// Round 4
// 947.533 us; speedup vs baseline: 1.3132x; 1.0825x over previous
//
#include <hip/hip_runtime.h>
#include <stdint.h>

#define C_DIM 2048
#define H_NUM 16
#define DH    128
#define S_LEN 1024
#define T_LEN 256
#define B_SZ  4
#define L_ROWS 4096   // B*S
#define LY_ROWS 1024  // B*T
#define F_DIM 8192

typedef __attribute__((ext_vector_type(4))) float f32x4;
typedef __attribute__((ext_vector_type(8))) __bf16 bf16x8;
typedef __attribute__((ext_vector_type(4))) unsigned short us4;
typedef __attribute__((ext_vector_type(8))) unsigned short us8;
typedef unsigned short u16;

__device__ __forceinline__ u16 f2bf(float f) {
  union { float f; uint32_t u; } v; v.f = f;
  uint32_t r = v.u + 0x7FFFu + ((v.u >> 16) & 1u);
  return (u16)(r >> 16);
}
__device__ __forceinline__ float bf2f(u16 h) {
  union { uint32_t u; float f; } v; v.u = ((uint32_t)h) << 16;
  return v.f;
}

typedef __attribute__((address_space(1))) void gvoid;
typedef __attribute__((address_space(3))) void lvoid;
__device__ __forceinline__ void gl_lds16(const void* g, void* l) {
  __builtin_amdgcn_global_load_lds((gvoid*)g, (lvoid*)l, 16, 0, 0);
}

template<int N> __device__ __forceinline__ void wait_vmcnt() {
  if constexpr (N == 0) asm volatile("s_waitcnt vmcnt(0)" ::: "memory");
  else if constexpr (N == 5) asm volatile("s_waitcnt vmcnt(5)" ::: "memory");
  else if constexpr (N == 6) asm volatile("s_waitcnt vmcnt(6)" ::: "memory");
}
__device__ __forceinline__ void barrier_raw() {
  asm volatile("s_barrier" ::: "memory");
}
__device__ __forceinline__ void lgkm0_pin() {
  asm volatile("s_waitcnt lgkmcnt(0)" ::: "memory");
  __builtin_amdgcn_sched_barrier(0);
}

// ---------------- fp32 -> bf16 conversion ----------------
__global__ void k_cvt(const float* __restrict__ src, u16* __restrict__ dst, int n) {
  int i = (blockIdx.x * blockDim.x + threadIdx.x) * 4;
  int stride = gridDim.x * blockDim.x * 4;
  for (; i < n; i += stride) {
    float4 v = *(const float4*)(src + i);
    us4 o;
    o[0] = f2bf(v.x); o[1] = f2bf(v.y); o[2] = f2bf(v.z); o[3] = f2bf(v.w);
    *(us4*)(dst + i) = o;
  }
}

// ---------------- LN + adaLN modulation ----------------
__global__ __launch_bounds__(256)
void k_modln(const float* __restrict__ x, const float* __restrict__ t,
             const float* __restrict__ tab, u16* __restrict__ out,
             int scale_idx, int shift_idx) {
  int row = blockIdx.x;
  int tid = threadIdx.x;
  const float* xr = x + (size_t)row * C_DIM;
  int c0 = tid * 8;
  float4 a = *(const float4*)(xr + c0);
  float4 b = *(const float4*)(xr + c0 + 4);
  float v[8] = {a.x, a.y, a.z, a.w, b.x, b.y, b.z, b.w};
  float s = 0.f, ss = 0.f;
#pragma unroll
  for (int j = 0; j < 8; ++j) { s += v[j]; ss += v[j] * v[j]; }
#pragma unroll
  for (int m = 1; m < 64; m <<= 1) { s += __shfl_xor(s, m); ss += __shfl_xor(ss, m); }
  __shared__ float red[8];
  int wid = tid >> 6;
  if ((tid & 63) == 0) { red[wid * 2] = s; red[wid * 2 + 1] = ss; }
  __syncthreads();
  s  = red[0] + red[2] + red[4] + red[6];
  ss = red[1] + red[3] + red[5] + red[7];
  float mean = s * (1.f / C_DIM);
  float var  = ss * (1.f / C_DIM) - mean * mean;
  float rstd = rsqrtf(var + 1e-6f);
  const float* trow = t + (size_t)row * (6 * C_DIM);
  const float* tsc = trow + scale_idx * C_DIM + c0;
  const float* tsh = trow + shift_idx * C_DIM + c0;
  const float* gsc = tab + scale_idx * C_DIM + c0;
  const float* gsh = tab + shift_idx * C_DIM + c0;
  us8 o;
#pragma unroll
  for (int j = 0; j < 8; ++j) {
    float scv = 1.f + gsc[j] + tsc[j];
    float shv = gsh[j] + tsh[j];
    o[j] = f2bf((v[j] - mean) * rstd * scv + shv);
  }
  *(us8*)(out + (size_t)row * C_DIM + c0) = o;
}

// ======== GEMM v3: BMx256 tile, BK=64, 4-phase deep pipeline (m201-class) ====
// out = A[M,K] @ W[N,K]^T (+epilogue). 512 threads = 8 waves (2M x 4N).
// LDS: A/B each 2-parity x 2-half; 2-bit XOR swizzle (byte bits 5,6 ^= row
// bits 2,3) applied on pre-swizzled global source + swizzled ds_read (#21).
// Stage ledger (steady state, iter kt issues): P1: A1(kt+1) [ACALLS];
// P3: B0,B1(kt+2) [4]; P4: A0(kt+2) [ACALLS]. End-of-iter wait must retire
// everything for tile kt+1 => may leave only the kt+2 stages outstanding:
// VMN = 4 + ACALLS  (R3 bug: had 4+2*ACALLS, leaving A1(kt+1) in flight).
// Region safety: A[p'] overwritten >=1 barrier after last read (P3 of kt-1);
// B[p] overwritten in P3 after its last read (P2) + barrier.
template<int BM, int EPI>
__global__ __launch_bounds__(512, 2)
void k_gemm3(const u16* __restrict__ A, const u16* __restrict__ W,
             const float* __restrict__ bias0, const float* __restrict__ bias1,
             const float* __restrict__ bias2,
             u16* __restrict__ o0, u16* __restrict__ o1, u16* __restrict__ o2,
             int sec_shift, int out_ld,
             float* __restrict__ outF, const float* __restrict__ resid,
             const float* __restrict__ gate_t, const float* __restrict__ gate_tab,
             int M, int N, int K, int nbx) {
  constexpr int HTA = (BM / 2) * 64;     // u16 per A half-tile
  constexpr int HTB = 128 * 64;          // u16 per B half-tile
  constexpr int ACALLS = BM / 128;       // gl_lds calls per A half (2 or 1)
  constexpr int QM = BM / 64;            // M-frags per quadrant (4 or 2)
  constexpr int MFR = BM / 32;           // M-frags per wave (8 or 4)
  constexpr int VMN = 4 + ACALLS;        // 5 (BM=128) / 6 (BM=256)
  constexpr int BOFF = 4 * HTA;
  __shared__ __align__(16) u16 lds[BOFF + 4 * HTB];

  int tid = threadIdx.x;
  // bijective XCD swizzle
  int nwg = gridDim.x;
  int q8 = nwg >> 3, r8 = nwg & 7;
  int xcd = blockIdx.x & 7, local = blockIdx.x >> 3;
  int wgid = (xcd < r8 ? xcd * (q8 + 1) : r8 * (q8 + 1) + (xcd - r8) * q8) + local;
  int bx = wgid % nbx, by = wgid / nbx;
  int m0 = by * BM, n0 = bx * 256;

  int wid = tid >> 6, lane = tid & 63;
  int wm = wid >> 2, wn = wid & 3;
  int lr = lane & 15, lg = lane >> 4;
  int xorslot = ((lr >> 2) & 3) << 1;    // read-side slot XOR (row bits 2,3)
  int bcol = (wn & 1) * 64;              // local col base within B half

  // stage-side source pre-swizzle (inverse of read-side XOR, involution)
  int tsw = tid ^ (((tid >> 5) & 1) << 1) ^ (((tid >> 6) & 1) << 2);
  int srow = tsw >> 3;                   // 0..63
  int scol = (tsw & 7) * 8;              // u16 col within 64-wide K-tile

  auto stA = [&](int h, int kt2) {
    int pt = kt2 & 1;
    u16* dst = lds + (pt * 2 + h) * HTA + tid * 8;
#pragma unroll
    for (int call = 0; call < ACALLS; ++call) {
      int grow = m0 + h * (BM / 2) + call * 64 + srow;
      gl_lds16(A + (size_t)grow * K + kt2 * 64 + scol, dst + call * 4096);
    }
  };
  auto stB = [&](int h, int kt2) {
    int pt = kt2 & 1;
    u16* dst = lds + BOFF + (pt * 2 + h) * HTB + tid * 8;
#pragma unroll
    for (int call = 0; call < 2; ++call) {
      int grow = n0 + h * 128 + call * 64 + srow;
      gl_lds16(W + (size_t)grow * K + kt2 * 64 + scol, dst + call * 4096);
    }
  };

  f32x4 zero4 = {0.f, 0.f, 0.f, 0.f};
  f32x4 acc[MFR][4];
#pragma unroll
  for (int m = 0; m < MFR; ++m)
#pragma unroll
    for (int n = 0; n < 4; ++n) acc[m][n] = zero4;

  int NT2 = K >> 6;
  // prologue: tile0 fully + {B0,B1,A0} of tile1 (leaves exactly VMN in flight)
  stA(0, 0); stA(1, 0); stB(0, 0); stB(1, 0);
  stB(0, 1); stB(1, 1); stA(0, 1);
  wait_vmcnt<VMN>();
  barrier_raw();

  for (int kt = 0; kt < NT2; ++kt) {
    int p = kt & 1;
    const u16* Ah = lds + (p * 2 + wm) * HTA;
    const u16* Bh = lds + BOFF + (p * 2 + (wn >> 1)) * HTB;
    bf16x8 aR[QM][2], bR0[2][2], bR1[2][2];
    bool st1 = (kt + 1) < NT2, st2 = (kt + 2) < NT2;

    // ---- P1: quadrant (mh=0, nh=0) ----
#pragma unroll
    for (int m = 0; m < QM; ++m) {
      int r = m * 16 + lr;
#pragma unroll
      for (int kk = 0; kk < 2; ++kk)
        aR[m][kk] = *(const bf16x8*)(Ah + r * 64 + (((kk << 2) | lg) ^ xorslot) * 8);
    }
#pragma unroll
    for (int n = 0; n < 2; ++n) {
      int r = bcol + n * 16 + lr;
#pragma unroll
      for (int kk = 0; kk < 2; ++kk)
        bR0[n][kk] = *(const bf16x8*)(Bh + r * 64 + (((kk << 2) | lg) ^ xorslot) * 8);
    }
    if (st1) stA(1, kt + 1);
    lgkm0_pin();
    __builtin_amdgcn_s_setprio(1);
#pragma unroll
    for (int kk = 0; kk < 2; ++kk)
#pragma unroll
      for (int m = 0; m < QM; ++m)
#pragma unroll
        for (int n = 0; n < 2; ++n)
          acc[m][n] = __builtin_amdgcn_mfma_f32_16x16x32_bf16(aR[m][kk], bR0[n][kk], acc[m][n], 0, 0, 0);
    __builtin_amdgcn_s_setprio(0);
    barrier_raw();

    // ---- P2: quadrant (mh=0, nh=1) ----
#pragma unroll
    for (int n = 0; n < 2; ++n) {
      int r = bcol + 32 + n * 16 + lr;
#pragma unroll
      for (int kk = 0; kk < 2; ++kk)
        bR1[n][kk] = *(const bf16x8*)(Bh + r * 64 + (((kk << 2) | lg) ^ xorslot) * 8);
    }
    lgkm0_pin();
    __builtin_amdgcn_s_setprio(1);
#pragma unroll
    for (int kk = 0; kk < 2; ++kk)
#pragma unroll
      for (int m = 0; m < QM; ++m)
#pragma unroll
        for (int n = 0; n < 2; ++n)
          acc[m][2 + n] = __builtin_amdgcn_mfma_f32_16x16x32_bf16(aR[m][kk], bR1[n][kk], acc[m][2 + n], 0, 0, 0);
    __builtin_amdgcn_s_setprio(0);
    barrier_raw();

    // ---- P3: quadrant (mh=1, nh=1) ----
#pragma unroll
    for (int m = 0; m < QM; ++m) {
      int r = (BM / 4) + m * 16 + lr;
#pragma unroll
      for (int kk = 0; kk < 2; ++kk)
        aR[m][kk] = *(const bf16x8*)(Ah + r * 64 + (((kk << 2) | lg) ^ xorslot) * 8);
    }
    if (st2) { stB(0, kt + 2); stB(1, kt + 2); }
    lgkm0_pin();
    __builtin_amdgcn_s_setprio(1);
#pragma unroll
    for (int kk = 0; kk < 2; ++kk)
#pragma unroll
      for (int m = 0; m < QM; ++m)
#pragma unroll
        for (int n = 0; n < 2; ++n)
          acc[QM + m][2 + n] = __builtin_amdgcn_mfma_f32_16x16x32_bf16(aR[m][kk], bR1[n][kk], acc[QM + m][2 + n], 0, 0, 0);
    __builtin_amdgcn_s_setprio(0);
    barrier_raw();

    // ---- P4: quadrant (mh=1, nh=0) ----
    if (st2) stA(0, kt + 2);
    __builtin_amdgcn_s_setprio(1);
#pragma unroll
    for (int kk = 0; kk < 2; ++kk)
#pragma unroll
      for (int m = 0; m < QM; ++m)
#pragma unroll
        for (int n = 0; n < 2; ++n)
          acc[QM + m][n] = __builtin_amdgcn_mfma_f32_16x16x32_bf16(aR[m][kk], bR0[n][kk], acc[QM + m][n], 0, 0, 0);
    __builtin_amdgcn_s_setprio(0);
    if (st2) wait_vmcnt<VMN>(); else wait_vmcnt<0>();
    barrier_raw();
  }

  // ---- epilogue ----
#pragma unroll
  for (int mf = 0; mf < MFR; ++mf) {
    int row0 = m0 + wm * (BM / 2) + mf * 16 + lg * 4;
#pragma unroll
    for (int nf = 0; nf < 4; ++nf) {
      int col = n0 + wn * 64 + nf * 16 + lr;
      if constexpr (EPI == 0) {
        int sec = col >> sec_shift;
        const float* bp = sec == 0 ? bias0 : (sec == 1 ? bias1 : bias2);
        u16* op = sec == 0 ? o0 : (sec == 1 ? o1 : o2);
        int cs = col & ((1 << sec_shift) - 1);
        float bv = bp[cs];
#pragma unroll
        for (int r = 0; r < 4; ++r)
          op[(size_t)(row0 + r) * out_ld + cs] = f2bf(acc[mf][nf][r] + bv);
      } else if constexpr (EPI == 1) {
        float bv = bias0[col];
#pragma unroll
        for (int r = 0; r < 4; ++r) {
          float val = acc[mf][nf][r] + bv;
          float x3 = val * val * val;
          float g = 0.5f * val * (1.f + tanhf(0.7978845608f * (val + 0.044715f * x3)));
          o0[(size_t)(row0 + r) * out_ld + col] = f2bf(g);
        }
      } else if constexpr (EPI == 2) {
        float bv = bias0[col];
        float gt = gate_tab[col];
#pragma unroll
        for (int r = 0; r < 4; ++r) {
          int row = row0 + r;
          size_t idx = (size_t)row * N + col;
          float g = gt + gate_t[(size_t)row * (6 * C_DIM) + col];
          float o = resid[idx] + g * (acc[mf][nf][r] + bv);
          outF[idx] = o;
          if (o0) o0[idx] = f2bf(o);
        }
      } else {
        float bv = bias0[col];
#pragma unroll
        for (int r = 0; r < 4; ++r) {
          size_t idx = (size_t)(row0 + r) * N + col;
          outF[idx] = resid[idx] + (acc[mf][nf][r] + bv);
        }
      }
    }
  }
}

// ---------------- RoPE on q and k (in place, bf16) ----------------
__global__ void k_rope(u16* __restrict__ q, u16* __restrict__ k,
                       const float* __restrict__ freqs) {
  int idx = blockIdx.x * blockDim.x + threadIdx.x;
  int total = L_ROWS * C_DIM / 8;
  for (; idx < total; idx += gridDim.x * blockDim.x) {
    int e = idx * 8;
    int row = e >> 11;
    int col = e & (C_DIM - 1);
    int s = row & (S_LEN - 1);
    int i0 = (col & (DH - 1)) >> 1;
    float4 fr = *(const float4*)(freqs + s * (DH / 2) + i0);
    float cs[4], sn[4];
    float fv[4] = {fr.x, fr.y, fr.z, fr.w};
#pragma unroll
    for (int j = 0; j < 4; ++j) sincosf(fv[j], &sn[j], &cs[j]);
    us8 qa = *(us8*)(q + e);
    us8 ka = *(us8*)(k + e);
#pragma unroll
    for (int p = 0; p < 4; ++p) {
      float a = bf2f(qa[2 * p]), b = bf2f(qa[2 * p + 1]);
      qa[2 * p]     = f2bf(a * cs[p] - b * sn[p]);
      qa[2 * p + 1] = f2bf(a * sn[p] + b * cs[p]);
      float a2 = bf2f(ka[2 * p]), b2 = bf2f(ka[2 * p + 1]);
      ka[2 * p]     = f2bf(a2 * cs[p] - b2 * sn[p]);
      ka[2 * p + 1] = f2bf(a2 * sn[p] + b2 * cs[p]);
    }
    *(us8*)(q + e) = qa;
    *(us8*)(k + e) = ka;
  }
}

// ---------------- V transpose: [b*Lkv+kv][h*DH+d] -> [bh][d][kv] ----------------
__global__ void k_transpose_v(const u16* __restrict__ v, u16* __restrict__ vt, int Lkv) {
  __shared__ u16 tile[32][33];
  int bh = blockIdx.x, b = bh >> 4, h = bh & 15;
  int k0 = blockIdx.y * 32, d0 = blockIdx.z * 32;
  int tx = threadIdx.x, ty = threadIdx.y;
  const u16* src = v + (size_t)(b * Lkv) * C_DIM + h * DH;
#pragma unroll
  for (int j = 0; j < 32; j += 8)
    tile[ty + j][tx] = src[(size_t)(k0 + ty + j) * C_DIM + d0 + tx];
  __syncthreads();
  u16* dst = vt + (size_t)bh * DH * Lkv;
#pragma unroll
  for (int j = 0; j < 32; j += 8)
    dst[(size_t)(d0 + ty + j) * Lkv + k0 + tx] = tile[tx][ty + j];
}

// ---------------- flash attention ----------------
__global__ __launch_bounds__(256)
void k_flash(const u16* __restrict__ Q, const u16* __restrict__ K,
             const u16* __restrict__ Vt, u16* __restrict__ O,
             int Lq, int Lkv, float scale) {
  __shared__ __align__(16) u16 lK[64 * 128];
  __shared__ __align__(16) u16 lV[128 * 64];
  __shared__ __align__(16) u16 lP[4][16 * 72];
  int bh = blockIdx.x, b = bh >> 4, h = bh & 15;
  int tid = threadIdx.x, wid = tid >> 6, lane = tid & 63;
  int lr = lane & 15, lg = lane >> 4;
  int q0 = blockIdx.y * 64 + wid * 16;
  const u16* Qb = Q + ((size_t)(b * Lq) + q0) * C_DIM + h * DH;
  const u16* Kb = K + (size_t)(b * Lkv) * C_DIM + h * DH;
  const u16* Vb = Vt + (size_t)bh * DH * Lkv;

  bf16x8 qf[4];
#pragma unroll
  for (int ks = 0; ks < 4; ++ks)
    qf[ks] = *(const bf16x8*)(Qb + (size_t)lr * C_DIM + ks * 32 + lg * 8);

  f32x4 zero4 = {0.f, 0.f, 0.f, 0.f};
  f32x4 o[8];
#pragma unroll
  for (int n = 0; n < 8; ++n) o[n] = zero4;
  float mrow[4] = {-3.0e38f, -3.0e38f, -3.0e38f, -3.0e38f};
  float lrow[4] = {0.f, 0.f, 0.f, 0.f};

  int nsteps = Lkv >> 6;
  for (int kt = 0; kt < nsteps; ++kt) {
#pragma unroll
    for (int i = 0; i < 4; ++i) {
      int flat = i * 4096 + tid * 16;
      int key = flat >> 8, inner = flat & 255;
      int ksrc = inner ^ ((key & 7) << 4);
      gl_lds16((const char*)Kb + ((size_t)(kt * 64 + key) * C_DIM) * 2 + ksrc, (char*)lK + flat);
      int d = flat >> 7, keyb = flat & 127;
      int vsrc = keyb ^ ((d & 7) << 4);
      gl_lds16((const char*)Vb + ((size_t)d * Lkv) * 2 + kt * 128 + vsrc, (char*)lV + flat);
    }
    __syncthreads();

    f32x4 sc[4];
#pragma unroll
    for (int c = 0; c < 4; ++c) sc[c] = zero4;
#pragma unroll
    for (int c = 0; c < 4; ++c) {
      int key = c * 16 + lr;
#pragma unroll
      for (int ks = 0; ks < 4; ++ks) {
        int off = (ks * 64 + lg * 16) ^ ((key & 7) << 4);
        bf16x8 kf = *(const bf16x8*)((const char*)lK + key * 256 + off);
        sc[c] = __builtin_amdgcn_mfma_f32_16x16x32_bf16(qf[ks], kf, sc[c], 0, 0, 0);
      }
    }
#pragma unroll
    for (int r = 0; r < 4; ++r) {
      float s0 = sc[0][r] * scale, s1 = sc[1][r] * scale;
      float s2 = sc[2][r] * scale, s3 = sc[3][r] * scale;
      float mx = fmaxf(fmaxf(s0, s1), fmaxf(s2, s3));
#pragma unroll
      for (int m = 1; m < 16; m <<= 1) mx = fmaxf(mx, __shfl_xor(mx, m));
      float mnew = fmaxf(mrow[r], mx);
      float alpha = exp2f((mrow[r] - mnew) * 1.44269504f);
      mrow[r] = mnew;
      float p0 = exp2f((s0 - mnew) * 1.44269504f);
      float p1 = exp2f((s1 - mnew) * 1.44269504f);
      float p2 = exp2f((s2 - mnew) * 1.44269504f);
      float p3 = exp2f((s3 - mnew) * 1.44269504f);
      float psum = p0 + p1 + p2 + p3;
#pragma unroll
      for (int m = 1; m < 16; m <<= 1) psum += __shfl_xor(psum, m);
      lrow[r] = lrow[r] * alpha + psum;
#pragma unroll
      for (int n = 0; n < 8; ++n) o[n][r] *= alpha;
      u16* pr = lP[wid] + (4 * lg + r) * 72;
      pr[lr]      = f2bf(p0);
      pr[16 + lr] = f2bf(p1);
      pr[32 + lr] = f2bf(p2);
      pr[48 + lr] = f2bf(p3);
    }
    asm volatile("s_waitcnt lgkmcnt(0)" ::: "memory");
    __builtin_amdgcn_sched_barrier(0);
#pragma unroll
    for (int half = 0; half < 2; ++half) {
      bf16x8 pf = *(const bf16x8*)(lP[wid] + lr * 72 + half * 32 + lg * 8);
#pragma unroll
      for (int n = 0; n < 8; ++n) {
        int d = n * 16 + lr;
        int off = (half * 64 + lg * 16) ^ ((d & 7) << 4);
        bf16x8 vf = *(const bf16x8*)((const char*)lV + d * 128 + off);
        o[n] = __builtin_amdgcn_mfma_f32_16x16x32_bf16(pf, vf, o[n], 0, 0, 0);
      }
    }
    __syncthreads();
  }

  u16* Ob = O + ((size_t)(b * Lq) + q0) * C_DIM + h * DH;
#pragma unroll
  for (int n = 0; n < 8; ++n) {
    int d = n * 16 + lr;
#pragma unroll
    for (int r = 0; r < 4; ++r) {
      int qr = 4 * lg + r;
      Ob[(size_t)qr * C_DIM + d] = f2bf(o[n][r] / lrow[r]);
    }
  }
}

// ---------------- host ----------------
extern "C" void kernel_launch(void* const* d_in, const int* in_sizes, int n_in,
                              void* d_out, int out_size, void* d_ws, size_t ws_size,
                              hipStream_t stream) {
  const float* x     = (const float*)d_in[0];
  const float* y     = (const float*)d_in[1];
  const float* t     = (const float*)d_in[2];
  const float* freqs = (const float*)d_in[3];
  const float* tab   = (const float*)d_in[4];
  const float* Wq_s = (const float*)d_in[5];
  const float* bq_s = (const float*)d_in[6];
  const float* Wk_s = (const float*)d_in[7];
  const float* bk_s = (const float*)d_in[8];
  const float* Wv_s = (const float*)d_in[9];
  const float* bv_s = (const float*)d_in[10];
  const float* Wo_s = (const float*)d_in[11];
  const float* bo_s = (const float*)d_in[12];
  const float* Wq_c = (const float*)d_in[13];
  const float* bq_c = (const float*)d_in[14];
  const float* Wk_c = (const float*)d_in[15];
  const float* bk_c = (const float*)d_in[16];
  const float* Wv_c = (const float*)d_in[17];
  const float* bv_c = (const float*)d_in[18];
  const float* Wo_c = (const float*)d_in[19];
  const float* bo_c = (const float*)d_in[20];
  const float* W_fc1 = (const float*)d_in[21];
  const float* b_fc1 = (const float*)d_in[22];
  const float* W_fc2 = (const float*)d_in[23];
  const float* b_fc2 = (const float*)d_in[24];

  const size_t SZ_CC  = (size_t)C_DIM * C_DIM * 2;
  const size_t SZ_FC  = (size_t)F_DIM * C_DIM * 2;
  const size_t SZ_LC  = (size_t)L_ROWS * C_DIM * 2;
  const size_t SZ_YC  = (size_t)LY_ROWS * C_DIM * 2;
  char* ws = (char*)d_ws;
  size_t off = 0;
  u16* wq_s = (u16*)(ws + off); off += SZ_CC;   // wq_s..wv_s contiguous = QKV concat
  u16* wk_s = (u16*)(ws + off); off += SZ_CC;
  u16* wv_s = (u16*)(ws + off); off += SZ_CC;
  u16* wo_s = (u16*)(ws + off); off += SZ_CC;
  u16* wq_c = (u16*)(ws + off); off += SZ_CC;
  u16* wk_c = (u16*)(ws + off); off += SZ_CC;   // wk_c,wv_c contiguous = KV concat
  u16* wv_c = (u16*)(ws + off); off += SZ_CC;
  u16* wo_c = (u16*)(ws + off); off += SZ_CC;
  u16* wfc1 = (u16*)(ws + off); off += SZ_FC;
  u16* wfc2 = (u16*)(ws + off); off += SZ_FC;
  u16* ybf  = (u16*)(ws + off); off += SZ_YC;
  u16* xm   = (u16*)(ws + off); off += SZ_LC;
  u16* qb   = (u16*)(ws + off); off += SZ_LC;
  u16* kb   = (u16*)(ws + off); off += SZ_LC;
  u16* vb   = (u16*)(ws + off); off += SZ_LC;
  u16* ao   = (u16*)(ws + off); off += SZ_LC;
  u16* hbuf = qb;                               // [L, F] bf16 overlay
  float* x1 = (float*)(ws + off); off += (size_t)L_ROWS * C_DIM * 4;
  u16* x1bf = (u16*)(ws + off); off += SZ_LC;
  u16* kc   = (u16*)(ws + off); off += SZ_YC;
  u16* vc   = (u16*)(ws + off); off += SZ_YC;
  u16* vt   = (u16*)(ws + off); off += SZ_LC;
  u16* vtc  = (u16*)(ws + off); off += SZ_YC;
  if (ws_size < off) return;

  auto cvt = [&](const float* s, u16* d, int n) {
    int blocks = (n / 4 + 255) / 256; if (blocks > 4096) blocks = 4096;
    k_cvt<<<blocks, 256, 0, stream>>>(s, d, n);
  };
  cvt(Wq_s, wq_s, C_DIM * C_DIM);
  cvt(Wk_s, wk_s, C_DIM * C_DIM);
  cvt(Wv_s, wv_s, C_DIM * C_DIM);
  cvt(Wo_s, wo_s, C_DIM * C_DIM);
  cvt(Wq_c, wq_c, C_DIM * C_DIM);
  cvt(Wk_c, wk_c, C_DIM * C_DIM);
  cvt(Wv_c, wv_c, C_DIM * C_DIM);
  cvt(Wo_c, wo_c, C_DIM * C_DIM);
  cvt(W_fc1, wfc1, F_DIM * C_DIM);
  cvt(W_fc2, wfc2, F_DIM * C_DIM);
  cvt(y, ybf, LY_ROWS * C_DIM);

  const float ascale = 0.08838834764831845f;

  k_modln<<<L_ROWS, 256, 0, stream>>>(x, t, tab, xm, 1, 0);
  // fused self QKV: N = 6144, weights = [wq_s;wk_s;wv_s]
  k_gemm3<128, 0><<<32 * 24, 512, 0, stream>>>(
      xm, wq_s, bq_s, bk_s, bv_s, qb, kb, vb, 11, C_DIM,
      nullptr, nullptr, nullptr, nullptr, L_ROWS, 6144, C_DIM, 24);
  k_rope<<<2048, 256, 0, stream>>>(qb, kb, freqs);
  k_transpose_v<<<dim3(B_SZ * H_NUM, S_LEN / 32, DH / 32), dim3(32, 8), 0, stream>>>(vb, vt, S_LEN);
  k_flash<<<dim3(B_SZ * H_NUM, S_LEN / 64), 256, 0, stream>>>(qb, kb, vt, ao, S_LEN, S_LEN, ascale);
  // x1 = x + gate_msa*(ao@Wo_s^T+bo_s); bf16 mirror x1bf
  k_gemm3<128, 2><<<32 * 8, 512, 0, stream>>>(
      ao, wo_s, bo_s, nullptr, nullptr, x1bf, nullptr, nullptr, 30, C_DIM,
      x1, x, t + 2 * C_DIM, tab + 2 * C_DIM, L_ROWS, C_DIM, C_DIM, 8);
  // cross q
  k_gemm3<128, 0><<<32 * 8, 512, 0, stream>>>(
      x1bf, wq_c, bq_c, nullptr, nullptr, qb, nullptr, nullptr, 30, C_DIM,
      nullptr, nullptr, nullptr, nullptr, L_ROWS, C_DIM, C_DIM, 8);
  // fused cross KV: N = 4096, weights = [wk_c;wv_c]
  k_gemm3<128, 0><<<8 * 16, 512, 0, stream>>>(
      ybf, wk_c, bk_c, bv_c, bv_c, kc, vc, vc, 11, C_DIM,
      nullptr, nullptr, nullptr, nullptr, LY_ROWS, 4096, C_DIM, 16);
  k_transpose_v<<<dim3(B_SZ * H_NUM, T_LEN / 32, DH / 32), dim3(32, 8), 0, stream>>>(vc, vtc, T_LEN);
  k_flash<<<dim3(B_SZ * H_NUM, S_LEN / 64), 256, 0, stream>>>(qb, kc, vtc, ao, S_LEN, T_LEN, ascale);
  // x1 += ao@Wo_c^T + bo_c
  k_gemm3<128, 3><<<32 * 8, 512, 0, stream>>>(
      ao, wo_c, bo_c, nullptr, nullptr, nullptr, nullptr, nullptr, 30, C_DIM,
      x1, x1, nullptr, nullptr, L_ROWS, C_DIM, C_DIM, 8);
  // MLP
  k_modln<<<L_ROWS, 256, 0, stream>>>(x1, t, tab, xm, 4, 3);
  k_gemm3<256, 1><<<16 * 32, 512, 0, stream>>>(
      xm, wfc1, b_fc1, nullptr, nullptr, hbuf, nullptr, nullptr, 30, F_DIM,
      nullptr, nullptr, nullptr, nullptr, L_ROWS, F_DIM, C_DIM, 32);
  k_gemm3<128, 2><<<32 * 8, 512, 0, stream>>>(
      hbuf, wfc2, b_fc2, nullptr, nullptr, nullptr, nullptr, nullptr, 30, C_DIM,
      (float*)d_out, x1, t + 5 * C_DIM, tab + 5 * C_DIM, L_ROWS, C_DIM, F_DIM, 8);
}

// Round 5
// 917.884 us; speedup vs baseline: 1.3557x; 1.0323x over previous
//
#include <hip/hip_runtime.h>
#include <stdint.h>

#define C_DIM 2048
#define H_NUM 16
#define DH    128
#define S_LEN 1024
#define T_LEN 256
#define B_SZ  4
#define L_ROWS 4096   // B*S
#define LY_ROWS 1024  // B*T
#define F_DIM 8192

typedef __attribute__((ext_vector_type(4))) float f32x4;
typedef __attribute__((ext_vector_type(8))) __bf16 bf16x8;
typedef __attribute__((ext_vector_type(4))) unsigned short us4;
typedef __attribute__((ext_vector_type(8))) unsigned short us8;
typedef unsigned short u16;

__device__ __forceinline__ u16 f2bf(float f) {
  union { float f; uint32_t u; } v; v.f = f;
  uint32_t r = v.u + 0x7FFFu + ((v.u >> 16) & 1u);
  return (u16)(r >> 16);
}
__device__ __forceinline__ float bf2f(u16 h) {
  union { uint32_t u; float f; } v; v.u = ((uint32_t)h) << 16;
  return v.f;
}

typedef __attribute__((address_space(1))) void gvoid;
typedef __attribute__((address_space(3))) void lvoid;
__device__ __forceinline__ void gl_lds16(const void* g, void* l) {
  __builtin_amdgcn_global_load_lds((gvoid*)g, (lvoid*)l, 16, 0, 0);
}

template<int N> __device__ __forceinline__ void wait_vmcnt() {
  if constexpr (N == 0) asm volatile("s_waitcnt vmcnt(0)" ::: "memory");
  else if constexpr (N == 5) asm volatile("s_waitcnt vmcnt(5)" ::: "memory");
  else if constexpr (N == 6) asm volatile("s_waitcnt vmcnt(6)" ::: "memory");
}
__device__ __forceinline__ void barrier_raw() {
  asm volatile("s_barrier" ::: "memory");
}
__device__ __forceinline__ void lgkm0_pin() {
  asm volatile("s_waitcnt lgkmcnt(0)" ::: "memory");
  __builtin_amdgcn_sched_barrier(0);
}

// ---------------- fp32 -> bf16 conversion ----------------
__global__ void k_cvt(const float* __restrict__ src, u16* __restrict__ dst, int n) {
  int i = (blockIdx.x * blockDim.x + threadIdx.x) * 4;
  int stride = gridDim.x * blockDim.x * 4;
  for (; i < n; i += stride) {
    float4 v = *(const float4*)(src + i);
    us4 o;
    o[0] = f2bf(v.x); o[1] = f2bf(v.y); o[2] = f2bf(v.z); o[3] = f2bf(v.w);
    *(us4*)(dst + i) = o;
  }
}

// ---------------- LN + adaLN modulation ----------------
__global__ __launch_bounds__(256)
void k_modln(const float* __restrict__ x, const float* __restrict__ t,
             const float* __restrict__ tab, u16* __restrict__ out,
             int scale_idx, int shift_idx) {
  int row = blockIdx.x;
  int tid = threadIdx.x;
  const float* xr = x + (size_t)row * C_DIM;
  int c0 = tid * 8;
  float4 a = *(const float4*)(xr + c0);
  float4 b = *(const float4*)(xr + c0 + 4);
  float v[8] = {a.x, a.y, a.z, a.w, b.x, b.y, b.z, b.w};
  float s = 0.f, ss = 0.f;
#pragma unroll
  for (int j = 0; j < 8; ++j) { s += v[j]; ss += v[j] * v[j]; }
#pragma unroll
  for (int m = 1; m < 64; m <<= 1) { s += __shfl_xor(s, m); ss += __shfl_xor(ss, m); }
  __shared__ float red[8];
  int wid = tid >> 6;
  if ((tid & 63) == 0) { red[wid * 2] = s; red[wid * 2 + 1] = ss; }
  __syncthreads();
  s  = red[0] + red[2] + red[4] + red[6];
  ss = red[1] + red[3] + red[5] + red[7];
  float mean = s * (1.f / C_DIM);
  float var  = ss * (1.f / C_DIM) - mean * mean;
  float rstd = rsqrtf(var + 1e-6f);
  const float* trow = t + (size_t)row * (6 * C_DIM);
  const float* tsc = trow + scale_idx * C_DIM + c0;
  const float* tsh = trow + shift_idx * C_DIM + c0;
  const float* gsc = tab + scale_idx * C_DIM + c0;
  const float* gsh = tab + shift_idx * C_DIM + c0;
  us8 o;
#pragma unroll
  for (int j = 0; j < 8; ++j) {
    float scv = 1.f + gsc[j] + tsc[j];
    float shv = gsh[j] + tsh[j];
    o[j] = f2bf((v[j] - mean) * rstd * scv + shv);
  }
  *(us8*)(out + (size_t)row * C_DIM + c0) = o;
}

// ======== GEMM v3b: BMx256 tile, BK=64, 4-phase pipeline, 3-bit swizzle ====
// out = A[M,K](ld=lda) @ W[N,K](ld=ldw)^T (+epilogue). 512 thr = 8 waves.
// LDS slot swizzle: logical 16B slot s of row r stored at s^(r&7); applied
// involutively on the global SOURCE (linear gl_lds dest) and on ds_read.
// Within a 16-lane quarter-wave (lg fixed, lr 0..15) slots cover all 8
// bank-groups twice -> 2-way = free (m136). R4 bug: slot bit0 was lg-only.
// Stage ledger: P1: A1(kt+1); P3: B0,B1(kt+2); P4: A0(kt+2);
// end-of-iter vmcnt(VMN = 4+ACALLS) retires everything for tile kt+1.
// EPI 0: bf16(acc+bias) -> o{0,1,2} by col>>sec_shift   EPI 1: gelu->o0
// EPI 2: outF = resid + gate*(acc+bias) (+o0 bf16)      EPI 3: outF=resid+acc+bias
// EPI 4: outF(fp32,ld=N) = acc (split-K partial)
// EPI 5: outF = resid + gate*(acc+partial+bias)
template<int BM, int EPI>
__global__ __launch_bounds__(512, 2)
void k_gemm3(const u16* __restrict__ A, const u16* __restrict__ W,
             const float* __restrict__ bias0, const float* __restrict__ bias1,
             const float* __restrict__ bias2,
             u16* __restrict__ o0, u16* __restrict__ o1, u16* __restrict__ o2,
             int sec_shift, int out_ld,
             float* __restrict__ outF, const float* __restrict__ resid,
             const float* __restrict__ gate_t, const float* __restrict__ gate_tab,
             const float* __restrict__ partial,
             int M, int N, int K, int lda, int ldw, int nbx) {
  constexpr int HTA = (BM / 2) * 64;
  constexpr int HTB = 128 * 64;
  constexpr int ACALLS = BM / 128;
  constexpr int QM = BM / 64;
  constexpr int MFR = BM / 32;
  constexpr int VMN = 4 + ACALLS;
  constexpr int BOFF = 4 * HTA;
  __shared__ __align__(16) u16 lds[BOFF + 4 * HTB];

  int tid = threadIdx.x;
  int nwg = gridDim.x;
  int q8 = nwg >> 3, r8 = nwg & 7;
  int xcd = blockIdx.x & 7, local = blockIdx.x >> 3;
  int wgid = (xcd < r8 ? xcd * (q8 + 1) : r8 * (q8 + 1) + (xcd - r8) * q8) + local;
  int bx = wgid % nbx, by = wgid / nbx;
  int m0 = by * BM, n0 = bx * 256;

  int wid = tid >> 6, lane = tid & 63;
  int wm = wid >> 2, wn = wid & 3;
  int lr = lane & 15, lg = lane >> 4;
  int xorslot = lr & 7;                  // 3-bit read-side slot XOR (row&7)
  int bcol = (wn & 1) * 64;

  // stage-side involutive source pre-swizzle: lane tid owns LDS (row=tid>>3,
  // slot=tid&7); it must fetch global col-slot (tid&7)^(row&7).
  int srow = tid >> 3;                   // 0..63
  int scol = ((tid ^ (tid >> 3)) & 7) * 8;

  auto stA = [&](int h, int kt2) {
    int pt = kt2 & 1;
    u16* dst = lds + (pt * 2 + h) * HTA + tid * 8;
#pragma unroll
    for (int call = 0; call < ACALLS; ++call) {
      int grow = m0 + h * (BM / 2) + call * 64 + srow;
      gl_lds16(A + (size_t)grow * lda + kt2 * 64 + scol, dst + call * 4096);
    }
  };
  auto stB = [&](int h, int kt2) {
    int pt = kt2 & 1;
    u16* dst = lds + BOFF + (pt * 2 + h) * HTB + tid * 8;
#pragma unroll
    for (int call = 0; call < 2; ++call) {
      int grow = n0 + h * 128 + call * 64 + srow;
      gl_lds16(W + (size_t)grow * ldw + kt2 * 64 + scol, dst + call * 4096);
    }
  };

  f32x4 zero4 = {0.f, 0.f, 0.f, 0.f};
  f32x4 acc[MFR][4];
#pragma unroll
  for (int m = 0; m < MFR; ++m)
#pragma unroll
    for (int n = 0; n < 4; ++n) acc[m][n] = zero4;

  int NT2 = K >> 6;
  stA(0, 0); stA(1, 0); stB(0, 0); stB(1, 0);
  stB(0, 1); stB(1, 1); stA(0, 1);
  wait_vmcnt<VMN>();
  barrier_raw();

  for (int kt = 0; kt < NT2; ++kt) {
    int p = kt & 1;
    const u16* Ah = lds + (p * 2 + wm) * HTA;
    const u16* Bh = lds + BOFF + (p * 2 + (wn >> 1)) * HTB;
    bf16x8 aR[QM][2], bR0[2][2], bR1[2][2];
    bool st1 = (kt + 1) < NT2, st2 = (kt + 2) < NT2;

    // ---- P1: quadrant (mh=0, nh=0) ----
#pragma unroll
    for (int m = 0; m < QM; ++m) {
      int r = m * 16 + lr;
#pragma unroll
      for (int kk = 0; kk < 2; ++kk)
        aR[m][kk] = *(const bf16x8*)(Ah + r * 64 + ((((kk << 2) | lg) ^ xorslot)) * 8);
    }
#pragma unroll
    for (int n = 0; n < 2; ++n) {
      int r = bcol + n * 16 + lr;
#pragma unroll
      for (int kk = 0; kk < 2; ++kk)
        bR0[n][kk] = *(const bf16x8*)(Bh + r * 64 + ((((kk << 2) | lg) ^ xorslot)) * 8);
    }
    if (st1) stA(1, kt + 1);
    lgkm0_pin();
    __builtin_amdgcn_s_setprio(1);
#pragma unroll
    for (int kk = 0; kk < 2; ++kk)
#pragma unroll
      for (int m = 0; m < QM; ++m)
#pragma unroll
        for (int n = 0; n < 2; ++n)
          acc[m][n] = __builtin_amdgcn_mfma_f32_16x16x32_bf16(aR[m][kk], bR0[n][kk], acc[m][n], 0, 0, 0);
    __builtin_amdgcn_s_setprio(0);
    barrier_raw();

    // ---- P2: quadrant (mh=0, nh=1) ----
#pragma unroll
    for (int n = 0; n < 2; ++n) {
      int r = bcol + 32 + n * 16 + lr;
#pragma unroll
      for (int kk = 0; kk < 2; ++kk)
        bR1[n][kk] = *(const bf16x8*)(Bh + r * 64 + ((((kk << 2) | lg) ^ xorslot)) * 8);
    }
    lgkm0_pin();
    __builtin_amdgcn_s_setprio(1);
#pragma unroll
    for (int kk = 0; kk < 2; ++kk)
#pragma unroll
      for (int m = 0; m < QM; ++m)
#pragma unroll
        for (int n = 0; n < 2; ++n)
          acc[m][2 + n] = __builtin_amdgcn_mfma_f32_16x16x32_bf16(aR[m][kk], bR1[n][kk], acc[m][2 + n], 0, 0, 0);
    __builtin_amdgcn_s_setprio(0);
    barrier_raw();

    // ---- P3: quadrant (mh=1, nh=1) ----
#pragma unroll
    for (int m = 0; m < QM; ++m) {
      int r = (BM / 4) + m * 16 + lr;
#pragma unroll
      for (int kk = 0; kk < 2; ++kk)
        aR[m][kk] = *(const bf16x8*)(Ah + r * 64 + ((((kk << 2) | lg) ^ xorslot)) * 8);
    }
    if (st2) { stB(0, kt + 2); stB(1, kt + 2); }
    lgkm0_pin();
    __builtin_amdgcn_s_setprio(1);
#pragma unroll
    for (int kk = 0; kk < 2; ++kk)
#pragma unroll
      for (int m = 0; m < QM; ++m)
#pragma unroll
        for (int n = 0; n < 2; ++n)
          acc[QM + m][2 + n] = __builtin_amdgcn_mfma_f32_16x16x32_bf16(aR[m][kk], bR1[n][kk], acc[QM + m][2 + n], 0, 0, 0);
    __builtin_amdgcn_s_setprio(0);
    barrier_raw();

    // ---- P4: quadrant (mh=1, nh=0) ----
    if (st2) stA(0, kt + 2);
    __builtin_amdgcn_s_setprio(1);
#pragma unroll
    for (int kk = 0; kk < 2; ++kk)
#pragma unroll
      for (int m = 0; m < QM; ++m)
#pragma unroll
        for (int n = 0; n < 2; ++n)
          acc[QM + m][n] = __builtin_amdgcn_mfma_f32_16x16x32_bf16(aR[m][kk], bR0[n][kk], acc[QM + m][n], 0, 0, 0);
    __builtin_amdgcn_s_setprio(0);
    if (st2) wait_vmcnt<VMN>(); else wait_vmcnt<0>();
    barrier_raw();
  }

  // ---- epilogue ----
#pragma unroll
  for (int mf = 0; mf < MFR; ++mf) {
    int row0 = m0 + wm * (BM / 2) + mf * 16 + lg * 4;
#pragma unroll
    for (int nf = 0; nf < 4; ++nf) {
      int col = n0 + wn * 64 + nf * 16 + lr;
      if constexpr (EPI == 0) {
        int sec = col >> sec_shift;
        const float* bp = sec == 0 ? bias0 : (sec == 1 ? bias1 : bias2);
        u16* op = sec == 0 ? o0 : (sec == 1 ? o1 : o2);
        int cs = col & ((1 << sec_shift) - 1);
        float bv = bp[cs];
#pragma unroll
        for (int r = 0; r < 4; ++r)
          op[(size_t)(row0 + r) * out_ld + cs] = f2bf(acc[mf][nf][r] + bv);
      } else if constexpr (EPI == 1) {
        float bv = bias0[col];
#pragma unroll
        for (int r = 0; r < 4; ++r) {
          float val = acc[mf][nf][r] + bv;
          float x3 = val * val * val;
          float g = 0.5f * val * (1.f + tanhf(0.7978845608f * (val + 0.044715f * x3)));
          o0[(size_t)(row0 + r) * out_ld + col] = f2bf(g);
        }
      } else if constexpr (EPI == 2) {
        float bv = bias0[col];
        float gt = gate_tab[col];
#pragma unroll
        for (int r = 0; r < 4; ++r) {
          int row = row0 + r;
          size_t idx = (size_t)row * N + col;
          float g = gt + gate_t[(size_t)row * (6 * C_DIM) + col];
          float o = resid[idx] + g * (acc[mf][nf][r] + bv);
          outF[idx] = o;
          if (o0) o0[idx] = f2bf(o);
        }
      } else if constexpr (EPI == 3) {
        float bv = bias0[col];
#pragma unroll
        for (int r = 0; r < 4; ++r) {
          size_t idx = (size_t)(row0 + r) * N + col;
          outF[idx] = resid[idx] + (acc[mf][nf][r] + bv);
        }
      } else if constexpr (EPI == 4) {
#pragma unroll
        for (int r = 0; r < 4; ++r)
          outF[(size_t)(row0 + r) * N + col] = acc[mf][nf][r];
      } else {  // EPI == 5: split-K finish + gate residual
        float bv = bias0[col];
        float gt = gate_tab[col];
#pragma unroll
        for (int r = 0; r < 4; ++r) {
          int row = row0 + r;
          size_t idx = (size_t)row * N + col;
          float val = acc[mf][nf][r] + partial[idx] + bv;
          float g = gt + gate_t[(size_t)row * (6 * C_DIM) + col];
          outF[idx] = resid[idx] + g * val;
        }
      }
    }
  }
}

// ---------------- RoPE on q and k (in place, bf16) ----------------
__global__ void k_rope(u16* __restrict__ q, u16* __restrict__ k,
                       const float* __restrict__ freqs) {
  int idx = blockIdx.x * blockDim.x + threadIdx.x;
  int total = L_ROWS * C_DIM / 8;
  for (; idx < total; idx += gridDim.x * blockDim.x) {
    int e = idx * 8;
    int row = e >> 11;
    int col = e & (C_DIM - 1);
    int s = row & (S_LEN - 1);
    int i0 = (col & (DH - 1)) >> 1;
    float4 fr = *(const float4*)(freqs + s * (DH / 2) + i0);
    float cs[4], sn[4];
    float fv[4] = {fr.x, fr.y, fr.z, fr.w};
#pragma unroll
    for (int j = 0; j < 4; ++j) sincosf(fv[j], &sn[j], &cs[j]);
    us8 qa = *(us8*)(q + e);
    us8 ka = *(us8*)(k + e);
#pragma unroll
    for (int p = 0; p < 4; ++p) {
      float a = bf2f(qa[2 * p]), b = bf2f(qa[2 * p + 1]);
      qa[2 * p]     = f2bf(a * cs[p] - b * sn[p]);
      qa[2 * p + 1] = f2bf(a * sn[p] + b * cs[p]);
      float a2 = bf2f(ka[2 * p]), b2 = bf2f(ka[2 * p + 1]);
      ka[2 * p]     = f2bf(a2 * cs[p] - b2 * sn[p]);
      ka[2 * p + 1] = f2bf(a2 * sn[p] + b2 * cs[p]);
    }
    *(us8*)(q + e) = qa;
    *(us8*)(k + e) = ka;
  }
}

// ---------------- V transpose: [b*Lkv+kv][h*DH+d] -> [bh][d][kv] ----------------
__global__ void k_transpose_v(const u16* __restrict__ v, u16* __restrict__ vt, int Lkv) {
  __shared__ u16 tile[32][33];
  int bh = blockIdx.x, b = bh >> 4, h = bh & 15;
  int k0 = blockIdx.y * 32, d0 = blockIdx.z * 32;
  int tx = threadIdx.x, ty = threadIdx.y;
  const u16* src = v + (size_t)(b * Lkv) * C_DIM + h * DH;
#pragma unroll
  for (int j = 0; j < 32; j += 8)
    tile[ty + j][tx] = src[(size_t)(k0 + ty + j) * C_DIM + d0 + tx];
  __syncthreads();
  u16* dst = vt + (size_t)bh * DH * Lkv;
#pragma unroll
  for (int j = 0; j < 32; j += 8)
    dst[(size_t)(d0 + ty + j) * Lkv + k0 + tx] = tile[tx][ty + j];
}

// ---------------- flash attention ----------------
__global__ __launch_bounds__(256)
void k_flash(const u16* __restrict__ Q, const u16* __restrict__ K,
             const u16* __restrict__ Vt, u16* __restrict__ O,
             int Lq, int Lkv, float scale) {
  __shared__ __align__(16) u16 lK[64 * 128];
  __shared__ __align__(16) u16 lV[128 * 64];
  __shared__ __align__(16) u16 lP[4][16 * 72];
  int bh = blockIdx.x, b = bh >> 4, h = bh & 15;
  int tid = threadIdx.x, wid = tid >> 6, lane = tid & 63;
  int lr = lane & 15, lg = lane >> 4;
  int q0 = blockIdx.y * 64 + wid * 16;
  const u16* Qb = Q + ((size_t)(b * Lq) + q0) * C_DIM + h * DH;
  const u16* Kb = K + (size_t)(b * Lkv) * C_DIM + h * DH;
  const u16* Vb = Vt + (size_t)bh * DH * Lkv;

  bf16x8 qf[4];
#pragma unroll
  for (int ks = 0; ks < 4; ++ks)
    qf[ks] = *(const bf16x8*)(Qb + (size_t)lr * C_DIM + ks * 32 + lg * 8);

  f32x4 zero4 = {0.f, 0.f, 0.f, 0.f};
  f32x4 o[8];
#pragma unroll
  for (int n = 0; n < 8; ++n) o[n] = zero4;
  float mrow[4] = {-3.0e38f, -3.0e38f, -3.0e38f, -3.0e38f};
  float lrow[4] = {0.f, 0.f, 0.f, 0.f};

  int nsteps = Lkv >> 6;
  for (int kt = 0; kt < nsteps; ++kt) {
#pragma unroll
    for (int i = 0; i < 4; ++i) {
      int flat = i * 4096 + tid * 16;
      int key = flat >> 8, inner = flat & 255;
      int ksrc = inner ^ ((key & 7) << 4);
      gl_lds16((const char*)Kb + ((size_t)(kt * 64 + key) * C_DIM) * 2 + ksrc, (char*)lK + flat);
      int d = flat >> 7, keyb = flat & 127;
      int vsrc = keyb ^ ((d & 7) << 4);
      gl_lds16((const char*)Vb + ((size_t)d * Lkv) * 2 + kt * 128 + vsrc, (char*)lV + flat);
    }
    __syncthreads();

    f32x4 sc[4];
#pragma unroll
    for (int c = 0; c < 4; ++c) sc[c] = zero4;
#pragma unroll
    for (int c = 0; c < 4; ++c) {
      int key = c * 16 + lr;
#pragma unroll
      for (int ks = 0; ks < 4; ++ks) {
        int off = (ks * 64 + lg * 16) ^ ((key & 7) << 4);
        bf16x8 kf = *(const bf16x8*)((const char*)lK + key * 256 + off);
        sc[c] = __builtin_amdgcn_mfma_f32_16x16x32_bf16(qf[ks], kf, sc[c], 0, 0, 0);
      }
    }
#pragma unroll
    for (int r = 0; r < 4; ++r) {
      float s0 = sc[0][r] * scale, s1 = sc[1][r] * scale;
      float s2 = sc[2][r] * scale, s3 = sc[3][r] * scale;
      float mx = fmaxf(fmaxf(s0, s1), fmaxf(s2, s3));
#pragma unroll
      for (int m = 1; m < 16; m <<= 1) mx = fmaxf(mx, __shfl_xor(mx, m));
      float mnew = fmaxf(mrow[r], mx);
      float alpha = exp2f((mrow[r] - mnew) * 1.44269504f);
      mrow[r] = mnew;
      float p0 = exp2f((s0 - mnew) * 1.44269504f);
      float p1 = exp2f((s1 - mnew) * 1.44269504f);
      float p2 = exp2f((s2 - mnew) * 1.44269504f);
      float p3 = exp2f((s3 - mnew) * 1.44269504f);
      float psum = p0 + p1 + p2 + p3;
#pragma unroll
      for (int m = 1; m < 16; m <<= 1) psum += __shfl_xor(psum, m);
      lrow[r] = lrow[r] * alpha + psum;
#pragma unroll
      for (int n = 0; n < 8; ++n) o[n][r] *= alpha;
      u16* pr = lP[wid] + (4 * lg + r) * 72;
      pr[lr]      = f2bf(p0);
      pr[16 + lr] = f2bf(p1);
      pr[32 + lr] = f2bf(p2);
      pr[48 + lr] = f2bf(p3);
    }
    asm volatile("s_waitcnt lgkmcnt(0)" ::: "memory");
    __builtin_amdgcn_sched_barrier(0);
#pragma unroll
    for (int half = 0; half < 2; ++half) {
      bf16x8 pf = *(const bf16x8*)(lP[wid] + lr * 72 + half * 32 + lg * 8);
#pragma unroll
      for (int n = 0; n < 8; ++n) {
        int d = n * 16 + lr;
        int off = (half * 64 + lg * 16) ^ ((d & 7) << 4);
        bf16x8 vf = *(const bf16x8*)((const char*)lV + d * 128 + off);
        o[n] = __builtin_amdgcn_mfma_f32_16x16x32_bf16(pf, vf, o[n], 0, 0, 0);
      }
    }
    __syncthreads();
  }

  u16* Ob = O + ((size_t)(b * Lq) + q0) * C_DIM + h * DH;
#pragma unroll
  for (int n = 0; n < 8; ++n) {
    int d = n * 16 + lr;
#pragma unroll
    for (int r = 0; r < 4; ++r) {
      int qr = 4 * lg + r;
      Ob[(size_t)qr * C_DIM + d] = f2bf(o[n][r] / lrow[r]);
    }
  }
}

// ---------------- host ----------------
extern "C" void kernel_launch(void* const* d_in, const int* in_sizes, int n_in,
                              void* d_out, int out_size, void* d_ws, size_t ws_size,
                              hipStream_t stream) {
  const float* x     = (const float*)d_in[0];
  const float* y     = (const float*)d_in[1];
  const float* t     = (const float*)d_in[2];
  const float* freqs = (const float*)d_in[3];
  const float* tab   = (const float*)d_in[4];
  const float* Wq_s = (const float*)d_in[5];
  const float* bq_s = (const float*)d_in[6];
  const float* Wk_s = (const float*)d_in[7];
  const float* bk_s = (const float*)d_in[8];
  const float* Wv_s = (const float*)d_in[9];
  const float* bv_s = (const float*)d_in[10];
  const float* Wo_s = (const float*)d_in[11];
  const float* bo_s = (const float*)d_in[12];
  const float* Wq_c = (const float*)d_in[13];
  const float* bq_c = (const float*)d_in[14];
  const float* Wk_c = (const float*)d_in[15];
  const float* bk_c = (const float*)d_in[16];
  const float* Wv_c = (const float*)d_in[17];
  const float* bv_c = (const float*)d_in[18];
  const float* Wo_c = (const float*)d_in[19];
  const float* bo_c = (const float*)d_in[20];
  const float* W_fc1 = (const float*)d_in[21];
  const float* b_fc1 = (const float*)d_in[22];
  const float* W_fc2 = (const float*)d_in[23];
  const float* b_fc2 = (const float*)d_in[24];

  const size_t SZ_CC  = (size_t)C_DIM * C_DIM * 2;
  const size_t SZ_FC  = (size_t)F_DIM * C_DIM * 2;
  const size_t SZ_LC  = (size_t)L_ROWS * C_DIM * 2;
  const size_t SZ_YC  = (size_t)LY_ROWS * C_DIM * 2;
  char* ws = (char*)d_ws;
  size_t off = 0;
  u16* wq_s = (u16*)(ws + off); off += SZ_CC;   // wq_s..wv_s contiguous = QKV concat
  u16* wk_s = (u16*)(ws + off); off += SZ_CC;
  u16* wv_s = (u16*)(ws + off); off += SZ_CC;
  u16* wo_s = (u16*)(ws + off); off += SZ_CC;
  u16* wq_c = (u16*)(ws + off); off += SZ_CC;
  u16* wk_c = (u16*)(ws + off); off += SZ_CC;   // wk_c,wv_c contiguous = KV concat
  u16* wv_c = (u16*)(ws + off); off += SZ_CC;
  u16* wo_c = (u16*)(ws + off); off += SZ_CC;
  u16* wfc1 = (u16*)(ws + off); off += SZ_FC;
  u16* wfc2 = (u16*)(ws + off); off += SZ_FC;
  u16* ybf  = (u16*)(ws + off); off += SZ_YC;
  u16* xm   = (u16*)(ws + off); off += SZ_LC;
  u16* qb   = (u16*)(ws + off); off += SZ_LC;
  u16* kb   = (u16*)(ws + off); off += SZ_LC;
  u16* vb   = (u16*)(ws + off); off += SZ_LC;
  u16* ao   = (u16*)(ws + off); off += SZ_LC;
  u16* hbuf = qb;                               // [L, F] bf16 overlay (qb..ao)
  float* x1 = (float*)(ws + off); off += (size_t)L_ROWS * C_DIM * 4;
  u16* x1bf = (u16*)(ws + off); off += SZ_LC;
  u16* kc   = (u16*)(ws + off); off += SZ_YC;
  u16* vc   = (u16*)(ws + off); off += SZ_YC;
  u16* vt   = (u16*)(ws + off); off += SZ_LC;
  u16* vtc  = (u16*)(ws + off); off += SZ_YC;
  // split-K partial for fc2: overlay dead region x1bf..vtc (44.5 MB >= 33.5 MB)
  float* part = (float*)x1bf;
  if (ws_size < off) return;

  auto cvt = [&](const float* s, u16* d, int n) {
    int blocks = (n / 4 + 255) / 256; if (blocks > 4096) blocks = 4096;
    k_cvt<<<blocks, 256, 0, stream>>>(s, d, n);
  };
  cvt(Wq_s, wq_s, C_DIM * C_DIM);
  cvt(Wk_s, wk_s, C_DIM * C_DIM);
  cvt(Wv_s, wv_s, C_DIM * C_DIM);
  cvt(Wo_s, wo_s, C_DIM * C_DIM);
  cvt(Wq_c, wq_c, C_DIM * C_DIM);
  cvt(Wk_c, wk_c, C_DIM * C_DIM);
  cvt(Wv_c, wv_c, C_DIM * C_DIM);
  cvt(Wo_c, wo_c, C_DIM * C_DIM);
  cvt(W_fc1, wfc1, F_DIM * C_DIM);
  cvt(W_fc2, wfc2, F_DIM * C_DIM);
  cvt(y, ybf, LY_ROWS * C_DIM);

  const float ascale = 0.08838834764831845f;

  k_modln<<<L_ROWS, 256, 0, stream>>>(x, t, tab, xm, 1, 0);
  // fused self QKV: N = 6144
  k_gemm3<128, 0><<<32 * 24, 512, 0, stream>>>(
      xm, wq_s, bq_s, bk_s, bv_s, qb, kb, vb, 11, C_DIM,
      nullptr, nullptr, nullptr, nullptr, nullptr, L_ROWS, 6144, C_DIM, C_DIM, C_DIM, 24);
  k_rope<<<2048, 256, 0, stream>>>(qb, kb, freqs);
  k_transpose_v<<<dim3(B_SZ * H_NUM, S_LEN / 32, DH / 32), dim3(32, 8), 0, stream>>>(vb, vt, S_LEN);
  k_flash<<<dim3(B_SZ * H_NUM, S_LEN / 64), 256, 0, stream>>>(qb, kb, vt, ao, S_LEN, S_LEN, ascale);
  // x1 = x + gate_msa*(ao@Wo_s^T+bo_s); bf16 mirror x1bf
  k_gemm3<128, 2><<<32 * 8, 512, 0, stream>>>(
      ao, wo_s, bo_s, nullptr, nullptr, x1bf, nullptr, nullptr, 30, C_DIM,
      x1, x, t + 2 * C_DIM, tab + 2 * C_DIM, nullptr, L_ROWS, C_DIM, C_DIM, C_DIM, C_DIM, 8);
  // cross q
  k_gemm3<128, 0><<<32 * 8, 512, 0, stream>>>(
      x1bf, wq_c, bq_c, nullptr, nullptr, qb, nullptr, nullptr, 30, C_DIM,
      nullptr, nullptr, nullptr, nullptr, nullptr, L_ROWS, C_DIM, C_DIM, C_DIM, C_DIM, 8);
  // fused cross KV: N = 4096
  k_gemm3<128, 0><<<8 * 16, 512, 0, stream>>>(
      ybf, wk_c, bk_c, bv_c, bv_c, kc, vc, vc, 11, C_DIM,
      nullptr, nullptr, nullptr, nullptr, nullptr, LY_ROWS, 4096, C_DIM, C_DIM, C_DIM, 16);
  k_transpose_v<<<dim3(B_SZ * H_NUM, T_LEN / 32, DH / 32), dim3(32, 8), 0, stream>>>(vc, vtc, T_LEN);
  k_flash<<<dim3(B_SZ * H_NUM, S_LEN / 64), 256, 0, stream>>>(qb, kc, vtc, ao, S_LEN, T_LEN, ascale);
  // x1 += ao@Wo_c^T + bo_c
  k_gemm3<128, 3><<<32 * 8, 512, 0, stream>>>(
      ao, wo_c, bo_c, nullptr, nullptr, nullptr, nullptr, nullptr, 30, C_DIM,
      x1, x1, nullptr, nullptr, nullptr, L_ROWS, C_DIM, C_DIM, C_DIM, C_DIM, 8);
  // MLP
  k_modln<<<L_ROWS, 256, 0, stream>>>(x1, t, tab, xm, 4, 3);
  k_gemm3<256, 1><<<16 * 32, 512, 0, stream>>>(
      xm, wfc1, b_fc1, nullptr, nullptr, hbuf, nullptr, nullptr, 30, F_DIM,
      nullptr, nullptr, nullptr, nullptr, nullptr, L_ROWS, F_DIM, C_DIM, C_DIM, C_DIM, 32);
  // fc2 split-K=2: phase 1 -> fp32 partial (k in [0,4096))
  k_gemm3<128, 4><<<32 * 8, 512, 0, stream>>>(
      hbuf, wfc2, nullptr, nullptr, nullptr, nullptr, nullptr, nullptr, 30, C_DIM,
      part, nullptr, nullptr, nullptr, nullptr, L_ROWS, C_DIM, F_DIM / 2, F_DIM, F_DIM, 8);
  // fc2 phase 2: k in [4096,8192) + partial + bias + gate residual -> d_out
  k_gemm3<128, 5><<<32 * 8, 512, 0, stream>>>(
      hbuf + F_DIM / 2, wfc2 + F_DIM / 2, b_fc2, nullptr, nullptr, nullptr, nullptr, nullptr, 30, C_DIM,
      (float*)d_out, x1, t + 5 * C_DIM, tab + 5 * C_DIM, part,
      L_ROWS, C_DIM, F_DIM / 2, F_DIM, F_DIM, 8);
}